// Round 4
// baseline (809.106 us; speedup 1.0000x reference)
//
#include <hip/hip_runtime.h>
#include <math.h>

// Problem constants: B=2, T=2048, H=8, Dk=64, D=512
#define BB 2
#define TT 2048
#define HH 8
#define DK 64
#define DD 512
#define MM (BB * TT)

typedef unsigned int u32;
typedef unsigned short u16;
typedef __bf16 bf16x8 __attribute__((ext_vector_type(8)));
typedef float f32x4 __attribute__((ext_vector_type(4)));

template<int N> struct ic_t { static constexpr int v = N; };

union frag_u { bf16x8 f; u16 u[8]; u32 w[4]; };

// fp32 -> bf16 hi + bf16 lo (RNE both); x ~= hi + lo to ~2^-20 rel.
__device__ __forceinline__ void split2(float x, u16& h, u16& l) {
    u32 u = __float_as_uint(x);
    u32 hi = (u + 0x7fffu + ((u >> 16) & 1u)) >> 16;
    float hif = __uint_as_float(hi << 16);
    float lof = x - hif;                       // exact
    u32 ul = __float_as_uint(lof);
    u32 lo = (ul + 0x7fffu + ((ul >> 16) & 1u)) >> 16;
    h = (u16)hi; l = (u16)lo;
}
__device__ __forceinline__ u32 split_pack(float x) {
    u16 h, l; split2(x, h, l);
    return ((u32)h << 16) | (u32)l;
}

// ---------------------------------------------------------------------------
// Sinusoid position encoding (fp64 math to match numpy float64 path).
// ---------------------------------------------------------------------------
__global__ __launch_bounds__(256) void pe_kernel(float* __restrict__ pe) {
    int idx = blockIdx.x * 256 + threadIdx.x;
    int m   = idx >> 9;
    int col = idx & 511;
    int j   = col & 255;
    double inv_freq = exp((double)(-2 * j) * (9.210340371976184 / 512.0));
    double ang = (double)(TT - m) * inv_freq;
    pe[idx] = (col < 256) ? (float)sin(ang) : (float)cos(ang);
}

// ---------------------------------------------------------------------------
// Tiled fp32 GEMM + bias. BM=BN=64, BK=16, 256 thr, 4x4 micro-tile.
// ---------------------------------------------------------------------------
__global__ __launch_bounds__(256) void gemm_bias_kernel(
    const float* __restrict__ A, const float* __restrict__ W,
    const float* __restrict__ bias, float* __restrict__ C,
    int M, int N, int K) {
    __shared__ float As[16][68];
    __shared__ float Bs[16][68];

    const int tid = threadIdx.x;
    const int n0 = blockIdx.x * 64;
    const int m0 = blockIdx.y * 64;
    const int tx = tid & 15;
    const int ty = tid >> 4;

    const int ar = tid >> 2;
    const int ac = (tid & 3) << 2;
    const int bk = tid >> 4;
    const int bc = (tid & 15) << 2;

    float acc[4][4] = {};

    for (int k0 = 0; k0 < K; k0 += 16) {
        float4 av = *(const float4*)&A[(size_t)(m0 + ar) * K + k0 + ac];
        float4 bv = *(const float4*)&W[(size_t)(k0 + bk) * N + n0 + bc];
        As[ac + 0][ar] = av.x;
        As[ac + 1][ar] = av.y;
        As[ac + 2][ar] = av.z;
        As[ac + 3][ar] = av.w;
        *(float4*)&Bs[bk][bc] = bv;
        __syncthreads();
#pragma unroll
        for (int kk = 0; kk < 16; kk++) {
            float4 a = *(const float4*)&As[kk][ty << 2];
            float4 b = *(const float4*)&Bs[kk][tx << 2];
            acc[0][0] += a.x * b.x; acc[0][1] += a.x * b.y; acc[0][2] += a.x * b.z; acc[0][3] += a.x * b.w;
            acc[1][0] += a.y * b.x; acc[1][1] += a.y * b.y; acc[1][2] += a.y * b.z; acc[1][3] += a.y * b.w;
            acc[2][0] += a.z * b.x; acc[2][1] += a.z * b.y; acc[2][2] += a.z * b.z; acc[2][3] += a.z * b.w;
            acc[3][0] += a.w * b.x; acc[3][1] += a.w * b.y; acc[3][2] += a.w * b.z; acc[3][3] += a.w * b.w;
        }
        __syncthreads();
    }

    float4 bv4 = make_float4(0.f, 0.f, 0.f, 0.f);
    if (bias) bv4 = *(const float4*)&bias[n0 + (tx << 2)];
#pragma unroll
    for (int u = 0; u < 4; u++) {
        int row = m0 + (ty << 2) + u;
        float4 o = make_float4(acc[u][0] + bv4.x, acc[u][1] + bv4.y,
                               acc[u][2] + bv4.z, acc[u][3] + bv4.w);
        *(float4*)&C[(size_t)row * N + n0 + (tx << 2)] = o;
    }
}

// ---------------------------------------------------------------------------
// Bias-fold dots, PRESCALED by 1/8, stored HEAD-MAJOR:
//   cbk[(h*B + b)*T + t]  = 0.125 * content_bias[h] . k[b,t,h,:]
//   rbrk[h*2T + m]        = 0.125 * relative_bias[h] . relk[m,h,:]
// ---------------------------------------------------------------------------
__global__ __launch_bounds__(256) void bias_dots_kernel(
    const float* __restrict__ kmat, const float* __restrict__ relk,
    const float* __restrict__ cb, const float* __restrict__ rb,
    float* __restrict__ cbk, float* __restrict__ rbrk) {
    int idx = blockIdx.x * 256 + threadIdx.x;
    if (idx < BB * TT * HH) {
        int h = idx & (HH - 1);
        int bt = idx >> 3;                 // b*T + t
        int b = bt >> 11, t = bt & (TT - 1);
        const float* kp  = kmat + (size_t)idx * DK;
        const float* cbp = cb + h * DK;
        float s = 0.f;
#pragma unroll
        for (int d = 0; d < DK; d++) s += cbp[d] * kp[d];
        cbk[((size_t)h * BB + b) * TT + t] = s * 0.125f;
    } else {
        int i2 = idx - BB * TT * HH;       // m*H + h
        int h = i2 & (HH - 1);
        int m = i2 >> 3;
        const float* rp  = relk + (size_t)i2 * DK;
        const float* rbp = rb + h * DK;
        float s = 0.f;
#pragma unroll
        for (int d = 0; d < DK; d++) s += rbp[d] * rp[d];
        rbrk[(size_t)h * (2 * TT) + m] = s * 0.125f;
    }
}

// ---------------------------------------------------------------------------
// Prepack fp32 32x64 tiles into swizzled hi/lo bf16 granule layout (8 KB/tile,
// hi at [0,4KB), lo at [4,8KB)). The attn kernel raw-copies these into LDS.
//   mode 0: K tiles   (bid: b=bid>>9, h=(bid>>6)&7, jt=bid&63), B-frag layout
//   mode 1: R chunks  (bid: h=bid>>7, cidx=bid&127),            B-frag layout
//   mode 2: V tiles   (K-style bid), transposed V-frag layout
// K/R granule: g = nt*128 + n*8 + ((4s+kq+5n)&7)  [row n of 16, nt=row>>4,
//              d = s*32+kq*8+e]   -> frag read is phase-conflict-free.
// V granule:   g = ntd*64 + n*4 + ((kq+(n>>1))&3) [col d=ntd*16+n, j=kq*8+e]
// ---------------------------------------------------------------------------
__global__ __launch_bounds__(256) void prepack_kernel(
    const float* __restrict__ src, u16* __restrict__ dst, int mode) {
    __shared__ float tf[32][68];
    const int bid = blockIdx.x, tid = threadIdx.x;
    size_t soff;
    if (mode == 1) soff = ((size_t)(bid & 127) * 256 + (size_t)(bid >> 7)) * 64;
    else soff = ((size_t)(bid >> 9) * 2048 + (size_t)(bid & 63) * 32) * 512
                + (size_t)((bid >> 6) & 7) * 64;
    u16* dt = dst + (size_t)bid * 4096;
    const int r = tid >> 3, f = tid & 7;
    const float* p = src + soff + (size_t)r * 512 + (size_t)f * 8;
    float4 a  = *(const float4*)p;
    float4 b4 = *(const float4*)(p + 4);
    if (mode == 2) {
        *(float4*)&tf[r][f * 8]     = a;
        *(float4*)&tf[r][f * 8 + 4] = b4;
        __syncthreads();
        const int d = tid >> 2, kq = tid & 3;
        u32 hw[4], lw[4];
#pragma unroll
        for (int e = 0; e < 4; e++) {
            u16 h0, l0, h1, l1;
            split2(tf[kq * 8 + 2 * e][d], h0, l0);
            split2(tf[kq * 8 + 2 * e + 1][d], h1, l1);
            hw[e] = (u32)h0 | ((u32)h1 << 16);
            lw[e] = (u32)l0 | ((u32)l1 << 16);
        }
        const int n = d & 15;
        const int g = (d >> 4) * 64 + n * 4 + ((kq + (n >> 1)) & 3);
        *(uint4*)(dt + g * 8)        = make_uint4(hw[0], hw[1], hw[2], hw[3]);
        *(uint4*)(dt + 2048 + g * 8) = make_uint4(lw[0], lw[1], lw[2], lw[3]);
    } else {
        float xs[8] = {a.x, a.y, a.z, a.w, b4.x, b4.y, b4.z, b4.w};
        u32 hw[4], lw[4];
#pragma unroll
        for (int e = 0; e < 4; e++) {
            u16 h0, l0, h1, l1;
            split2(xs[2 * e], h0, l0);
            split2(xs[2 * e + 1], h1, l1);
            hw[e] = (u32)h0 | ((u32)h1 << 16);
            lw[e] = (u32)l0 | ((u32)l1 << 16);
        }
        const int s = f >> 2, kq = f & 3, nt = r >> 4, n = r & 15;
        const int g = nt * 128 + n * 8 + ((4 * s + kq + 5 * n) & 7);
        *(uint4*)(dt + g * 8)        = make_uint4(hw[0], hw[1], hw[2], hw[3]);
        *(uint4*)(dt + 2048 + g * 8) = make_uint4(lw[0], lw[1], lw[2], lw[3]);
    }
}

// ---------------------------------------------------------------------------
// MFMA flash attention with Transformer-XL rel-shift, bf16 hi/lo emulation.
// Block = (b, h, 64 Q rows), 4 waves, wave w owns rows 16w..16w+15.
//
// rel2 lives in an 8-slot REGISTER ring H[8][4] per thread, indexed by the
// diagonal coordinate y = T + j (slot = (2jt+nt)&7, value for row quad*4+r at
// lane c is exactly rel[row][j0+16nt+c] -- same C-layout as the S-tile, so
// the S-phase "gather" is a plain register add). produce() redistributes the
// chunk-m C-layout MFMA output into y-layout with 8 ds_bpermute + cndmask
// merges; slot indices are compile-time via jt%4 unroll + uniform w branch.
// K/V/R arrive prepacked; staging = reg-prefetch + raw ds_write_b128.
// ---------------------------------------------------------------------------
#define MRG(W) { \
    H[(P2 + W) & 7][r]     = cy ? H[(P2 + W) & 7][r] : v0; \
    H[(P2 + W + 1) & 7][r] = cy ? v0 : v1; \
    H[(P2 + W + 2) & 7][r] = cy ? v1 : H[(P2 + W + 2) & 7][r]; }

__global__ __launch_bounds__(256, 3) void attn_mfma_kernel(
    const float* __restrict__ q, const u16* __restrict__ Kpk,
    const u16* __restrict__ Vpk, const u16* __restrict__ Rpk,
    const float* __restrict__ cbk, const float* __restrict__ rbrk,
    float* __restrict__ attn_out) {
    __shared__ __align__(16) u16 Kbuf[4096];
    __shared__ __align__(16) u16 Vbuf[4096];
    __shared__ __align__(16) u16 Rbuf[4096];
    __shared__ u32 Pbuf[4 * 544];

    const int tid = threadIdx.x;
    const int w = tid >> 6, lane = tid & 63, quad = lane >> 4, c = lane & 15;
    const int bx = blockIdx.x;
    const int it0 = bx & 31, h = (bx >> 5) & 7, b = bx >> 8;
    const int i0 = it0 * 64;
    const size_t bh_off = (size_t)b * TT * DD + (size_t)h * DK;

    // ---- Q A-frags (hi/lo), prescaled 1/8; row = i0+16w+c, k = 32s+8quad+j
    frag_u qh[2], ql[2];
    {
        const float* qrow = q + bh_off + (size_t)(i0 + 16 * w + c) * DD;
#pragma unroll
        for (int s = 0; s < 2; s++) {
            int d0 = s * 32 + quad * 8;
            float4 a  = *(const float4*)(qrow + d0);
            float4 b4 = *(const float4*)(qrow + d0 + 4);
            float xs[8] = {a.x, a.y, a.z, a.w, b4.x, b4.y, b4.z, b4.w};
#pragma unroll
            for (int j2 = 0; j2 < 8; j2++)
                split2(xs[j2] * 0.125f, qh[s].u[j2], ql[s].u[j2]);
        }
    }

    const u16* Ktiles  = Kpk + (size_t)(b * HH + h) * 64 * 4096;
    const u16* Vtiles  = Vpk + (size_t)(b * HH + h) * 64 * 4096;
    const u16* Rchunks = Rpk + (size_t)h * 128 * 4096;
    const float* rbrk_h = rbrk + (size_t)h * (2 * TT);
    const float* cbk_h  = cbk + ((size_t)h * BB + b) * TT;

    float H[8][4];
#pragma unroll
    for (int s = 0; s < 8; s++)
#pragma unroll
        for (int r = 0; r < 4; r++) H[s][r] = 0.f;

    auto read_kr = [&](const u16* reg, int nt, int s, bf16x8& fh, bf16x8& fl) {
        int g = (nt << 7) + (c << 3) + (((s << 2) + quad + 5 * c) & 7);
        fh = *(const bf16x8*)(reg + g * 8);
        fl = *(const bf16x8*)(reg + 2048 + g * 8);
    };
    auto read_v = [&](int ntd, bf16x8& fh, bf16x8& fl) {
        int g = ntd * 64 + c * 4 + ((quad + (c >> 1)) & 3);
        fh = *(const bf16x8*)(Vbuf + g * 8);
        fl = *(const bf16x8*)(Vbuf + 2048 + g * 8);
    };

    // produce rel2 chunk cidx (32 m values) for this wave's 16 rows, then
    // redistribute into register ring H (y-diagonal layout). rbrk folded in.
    auto produce = [&](auto PC, int cidx) {
        constexpr int P2 = (2 * decltype(PC)::v) & 7;
        f32x4 rc[2];
#pragma unroll
        for (int ntp = 0; ntp < 2; ntp++) {
            f32x4 acc = {0.f, 0.f, 0.f, 0.f};
#pragma unroll
            for (int s = 0; s < 2; s++) {
                bf16x8 fh, fl;
                read_kr(Rbuf, ntp, s, fh, fl);
                acc = __builtin_amdgcn_mfma_f32_16x16x32_bf16(qh[s].f, fh, acc, 0, 0, 0);
                acc = __builtin_amdgcn_mfma_f32_16x16x32_bf16(qh[s].f, fl, acc, 0, 0, 0);
                acc = __builtin_amdgcn_mfma_f32_16x16x32_bf16(ql[s].f, fh, acc, 0, 0, 0);
            }
            float rbv = rbrk_h[cidx * 32 + ntp * 16 + c];
#pragma unroll
            for (int r = 0; r < 4; r++) acc[r] += rbv;
            rc[ntp] = acc;
        }
#pragma unroll
        for (int r = 0; r < 4; r++) {
            int srcl = (quad << 4) + ((c - 4 * quad - r) & 15);
            float v0 = __uint_as_float(__builtin_amdgcn_ds_bpermute(
                srcl << 2, __float_as_uint(rc[0][r])));
            float v1 = __uint_as_float(__builtin_amdgcn_ds_bpermute(
                srcl << 2, __float_as_uint(rc[1][r])));
            bool cy = c < (4 * quad + r);
            if (w == 0)      MRG(0)
            else if (w == 1) MRG(1)
            else if (w == 2) MRG(2)
            else             MRG(3)
        }
    };

    const int k0c = (TT - i0 - 63) >> 5;   // (TT-i0-63) % 32 == 1

    // ---- prologue: chunks k0c (virtual jt=-2 -> P2=4), k0c+1 (P2=6) ----
    {
        const uint4* rs = (const uint4*)(Rchunks + (size_t)k0c * 4096);
        ((uint4*)Rbuf)[tid] = rs[tid];
        ((uint4*)Rbuf)[tid + 256] = rs[tid + 256];
    }
    __syncthreads();
    produce(ic_t<2>{}, k0c);
    __syncthreads();
    {
        const uint4* rs = (const uint4*)(Rchunks + (size_t)(k0c + 1) * 4096);
        ((uint4*)Rbuf)[tid] = rs[tid];
        ((uint4*)Rbuf)[tid + 256] = rs[tid + 256];
    }
    __syncthreads();
    produce(ic_t<3>{}, k0c + 1);

    uint4 pf[6];
    auto prefetch = [&](int jn) {
        int jtc = jn < 63 ? jn : 63;
        const uint4* ks = (const uint4*)(Ktiles + (size_t)jtc * 4096);
        pf[0] = ks[tid]; pf[1] = ks[tid + 256];
        const uint4* vs = (const uint4*)(Vtiles + (size_t)jtc * 4096);
        pf[2] = vs[tid]; pf[3] = vs[tid + 256];
        int cidx = k0c + jn + 2; if (cidx > 127) cidx = 127;
        const uint4* rs = (const uint4*)(Rchunks + (size_t)cidx * 4096);
        pf[4] = rs[tid]; pf[5] = rs[tid + 256];
    };
    prefetch(0);

    float m_run[4], l_run[4];
    f32x4 o[4];
#pragma unroll
    for (int r = 0; r < 4; r++) { m_run[r] = -INFINITY; l_run[r] = 0.f; }
#pragma unroll
    for (int nt = 0; nt < 4; nt++) o[nt] = (f32x4){0.f, 0.f, 0.f, 0.f};

    auto body = [&](auto PC, int jt0) {
        constexpr int P = decltype(PC)::v;
        const int jt = jt0 + P;
        const int j0 = jt * 32;
        __syncthreads();   // prior iteration's LDS reads complete
        ((uint4*)Kbuf)[tid] = pf[0]; ((uint4*)Kbuf)[tid + 256] = pf[1];
        ((uint4*)Vbuf)[tid] = pf[2]; ((uint4*)Vbuf)[tid + 256] = pf[3];
        ((uint4*)Rbuf)[tid] = pf[4]; ((uint4*)Rbuf)[tid + 256] = pf[5];
        prefetch(jt + 1);  // next tiles in flight during compute
        __syncthreads();   // staged data visible
        produce(PC, k0c + jt + 2);

        // ---- S = QK (MFMA) + rel (register!) + cbk ----
        float sv[2][4];
#pragma unroll
        for (int nt = 0; nt < 2; nt++) {
            f32x4 sc = {0.f, 0.f, 0.f, 0.f};
#pragma unroll
            for (int s = 0; s < 2; s++) {
                bf16x8 fh, fl;
                read_kr(Kbuf, nt, s, fh, fl);
                sc = __builtin_amdgcn_mfma_f32_16x16x32_bf16(qh[s].f, fh, sc, 0, 0, 0);
                sc = __builtin_amdgcn_mfma_f32_16x16x32_bf16(qh[s].f, fl, sc, 0, 0, 0);
                sc = __builtin_amdgcn_mfma_f32_16x16x32_bf16(ql[s].f, fh, sc, 0, 0, 0);
            }
            float cbv = cbk_h[j0 + nt * 16 + c];
#pragma unroll
            for (int r = 0; r < 4; r++)
                sv[nt][r] = sc[r] + H[(2 * P + nt) & 7][r] + cbv;
        }

        // ---- online softmax (16 lanes per row) + P write (packed u32) ----
#pragma unroll
        for (int r = 0; r < 4; r++) {
            float tm = fmaxf(sv[0][r], sv[1][r]);
#pragma unroll
            for (int off = 1; off < 16; off <<= 1) tm = fmaxf(tm, __shfl_xor(tm, off));
            float mnew = fmaxf(m_run[r], tm);
            float al = __expf(m_run[r] - mnew);
            float p0 = __expf(sv[0][r] - mnew);
            float p1 = __expf(sv[1][r] - mnew);
            float ps = p0 + p1;
#pragma unroll
            for (int off = 1; off < 16; off <<= 1) ps += __shfl_xor(ps, off);
            l_run[r] = l_run[r] * al + ps;
            m_run[r] = mnew;
#pragma unroll
            for (int nt = 0; nt < 4; nt++) o[nt][r] *= al;
            u32* pb = Pbuf + w * 544 + (quad * 4 + r) * 34;
            pb[c]      = split_pack(p0);
            pb[16 + c] = split_pack(p1);
        }

        // ---- O += P @ V (hi/lo) ----
        frag_u ph, pl;
        {
            const u32* pb = Pbuf + w * 544 + c * 34 + quad * 8;
            uint2 r0 = *(const uint2*)(pb);
            uint2 r1 = *(const uint2*)(pb + 2);
            uint2 r2 = *(const uint2*)(pb + 4);
            uint2 r3 = *(const uint2*)(pb + 6);
            u32 pk[8] = {r0.x, r0.y, r1.x, r1.y, r2.x, r2.y, r3.x, r3.y};
#pragma unroll
            for (int j2 = 0; j2 < 8; j2++) {
                ph.u[j2] = (u16)(pk[j2] >> 16);
                pl.u[j2] = (u16)(pk[j2] & 0xffffu);
            }
        }
#pragma unroll
        for (int ntd = 0; ntd < 4; ntd++) {
            bf16x8 vh, vl;
            read_v(ntd, vh, vl);
            o[ntd] = __builtin_amdgcn_mfma_f32_16x16x32_bf16(ph.f, vh, o[ntd], 0, 0, 0);
            o[ntd] = __builtin_amdgcn_mfma_f32_16x16x32_bf16(ph.f, vl, o[ntd], 0, 0, 0);
            o[ntd] = __builtin_amdgcn_mfma_f32_16x16x32_bf16(pl.f, vh, o[ntd], 0, 0, 0);
        }
    };

    for (int jt0 = 0; jt0 < TT / 32; jt0 += 4) {
        body(ic_t<0>{}, jt0);
        body(ic_t<1>{}, jt0);
        body(ic_t<2>{}, jt0);
        body(ic_t<3>{}, jt0);
    }

    // ---- epilogue: normalize, store [B,T,H*Dk] ----
#pragma unroll
    for (int nt = 0; nt < 4; nt++) {
#pragma unroll
        for (int r = 0; r < 4; r++) {
            int row16 = quad * 4 + r;
            int i_abs = i0 + 16 * w + row16;
            attn_out[((size_t)b * TT + i_abs) * DD + h * DK + nt * 16 + c] =
                o[nt][r] / l_run[r];
        }
    }
}

// ---------------------------------------------------------------------------
extern "C" void kernel_launch(void* const* d_in, const int* in_sizes, int n_in,
                              void* d_out, int out_size, void* d_ws, size_t ws_size,
                              hipStream_t stream) {
    const float* query  = (const float*)d_in[0];
    const float* key_in = (const float*)d_in[1];
    const float* value  = (const float*)d_in[2];
    const float* Wq = (const float*)d_in[3];
    const float* bq = (const float*)d_in[4];
    const float* Wk = (const float*)d_in[5];
    const float* bk = (const float*)d_in[6];
    const float* Wv = (const float*)d_in[7];
    const float* bv = (const float*)d_in[8];
    const float* Wr = (const float*)d_in[9];
    const float* cb = (const float*)d_in[10];
    const float* rb = (const float*)d_in[11];
    const float* Wo = (const float*)d_in[12];
    const float* bo = (const float*)d_in[13];
    float* out = (float*)d_out;

    float* ws = (float*)d_ws;
    const size_t SL = (size_t)MM * DD;        // 2097152 floats per slot
    float* qb    = ws;                        // fp32 Q [B,T,H,Dk]
    float* kb    = ws + SL;                   // fp32 K (consumed, then holds Rpk)
    float* vb    = ws + 2 * SL;               // fp32 V (consumed, then holds Kpk)
    float* relk  = ws + 3 * SL;               // fp32 relK [2T,H,Dk]
    float* attnv = ws + 4 * SL;               // attn output (pe aliased here first)
    float* pe    = attnv;                     // pe consumed before attnv written
    u16*   Vpk   = (u16*)(ws + 5 * SL);       // packed V tiles (8 MB)
    u16*   Kpk   = (u16*)vb;                  // packed K tiles (8 MB)
    u16*   Rpk   = (u16*)kb;                  // packed R chunks (8 MB)
    float* cbk   = ws + 6 * SL;               // [H*B*T]
    float* rbrk  = cbk + BB * TT * HH;        // [H*2T]

    const dim3 gemm_grid(DD / 64, MM / 64);   // (8, 64)

    pe_kernel<<<(2 * TT * DD) / 256, 256, 0, stream>>>(pe);
    gemm_bias_kernel<<<gemm_grid, 256, 0, stream>>>(pe, Wr, nullptr, relk, MM, DD, DD);
    gemm_bias_kernel<<<gemm_grid, 256, 0, stream>>>(query,  Wq, bq, qb, MM, DD, DD);
    gemm_bias_kernel<<<gemm_grid, 256, 0, stream>>>(key_in, Wk, bk, kb, MM, DD, DD);
    gemm_bias_kernel<<<gemm_grid, 256, 0, stream>>>(value,  Wv, bv, vb, MM, DD, DD);
    bias_dots_kernel<<<(BB * TT * HH + 2 * TT * HH) / 256, 256, 0, stream>>>(
        kb, relk, cb, rb, cbk, rbrk);
    // prepack order matters (aliasing): V first (frees vb), then K (-> vb),
    // then R (-> kb, after K consumed kb).
    prepack_kernel<<<1024, 256, 0, stream>>>(vb, Vpk, 2);
    prepack_kernel<<<1024, 256, 0, stream>>>(kb, Kpk, 0);
    prepack_kernel<<<1024, 256, 0, stream>>>(relk, Rpk, 1);
    attn_mfma_kernel<<<BB * HH * (TT / 64), 256, 0, stream>>>(
        qb, Kpk, Vpk, Rpk, cbk, rbrk, attnv);
    gemm_bias_kernel<<<gemm_grid, 256, 0, stream>>>(attnv, Wo, bo, out, MM, DD, DD);
}

// Round 5
// 542.458 us; speedup vs baseline: 1.4916x; 1.4916x over previous
//
#include <hip/hip_runtime.h>
#include <math.h>

// Problem constants: B=2, T=2048, H=8, Dk=64, D=512
#define BB 2
#define TT 2048
#define HH 8
#define DK 64
#define DD 512
#define MM (BB * TT)

typedef unsigned int u32;
typedef unsigned short u16;
typedef __bf16 bf16x8 __attribute__((ext_vector_type(8)));
typedef float f32x4 __attribute__((ext_vector_type(4)));

template<int N> struct ic_t { static constexpr int v = N; };

union frag_u { bf16x8 f; u16 u[8]; u32 w[4]; };

// fp32 -> bf16 hi + bf16 lo (RNE both); x ~= hi + lo to ~2^-20 rel.
__device__ __forceinline__ void split2(float x, u16& h, u16& l) {
    u32 u = __float_as_uint(x);
    u32 hi = (u + 0x7fffu + ((u >> 16) & 1u)) >> 16;
    float hif = __uint_as_float(hi << 16);
    float lof = x - hif;                       // exact
    u32 ul = __float_as_uint(lof);
    u32 lo = (ul + 0x7fffu + ((ul >> 16) & 1u)) >> 16;
    h = (u16)hi; l = (u16)lo;
}
__device__ __forceinline__ u32 split_pack(float x) {
    u16 h, l; split2(x, h, l);
    return ((u32)h << 16) | (u32)l;
}

// async global->LDS, 16B per lane, dest = uniform base + lane*16
__device__ __forceinline__ void load_lds16(const void* g, void* l) {
    __builtin_amdgcn_global_load_lds(
        (const __attribute__((address_space(1))) void*)g,
        (__attribute__((address_space(3))) void*)l, 16, 0, 0);
}

// ---------------------------------------------------------------------------
// Sinusoid position encoding (fp64 math to match numpy float64 path).
// ---------------------------------------------------------------------------
__global__ __launch_bounds__(256) void pe_kernel(float* __restrict__ pe) {
    int idx = blockIdx.x * 256 + threadIdx.x;
    int m   = idx >> 9;
    int col = idx & 511;
    int j   = col & 255;
    double inv_freq = exp((double)(-2 * j) * (9.210340371976184 / 512.0));
    double ang = (double)(TT - m) * inv_freq;
    pe[idx] = (col < 256) ? (float)sin(ang) : (float)cos(ang);
}

// ---------------------------------------------------------------------------
// Tiled fp32 GEMM + bias. BM=BN=64, BK=16, 256 thr, 4x4 micro-tile.
// ---------------------------------------------------------------------------
__global__ __launch_bounds__(256) void gemm_bias_kernel(
    const float* __restrict__ A, const float* __restrict__ W,
    const float* __restrict__ bias, float* __restrict__ C,
    int M, int N, int K) {
    __shared__ float As[16][68];
    __shared__ float Bs[16][68];

    const int tid = threadIdx.x;
    const int n0 = blockIdx.x * 64;
    const int m0 = blockIdx.y * 64;
    const int tx = tid & 15;
    const int ty = tid >> 4;

    const int ar = tid >> 2;
    const int ac = (tid & 3) << 2;
    const int bk = tid >> 4;
    const int bc = (tid & 15) << 2;

    float acc[4][4] = {};

    for (int k0 = 0; k0 < K; k0 += 16) {
        float4 av = *(const float4*)&A[(size_t)(m0 + ar) * K + k0 + ac];
        float4 bv = *(const float4*)&W[(size_t)(k0 + bk) * N + n0 + bc];
        As[ac + 0][ar] = av.x;
        As[ac + 1][ar] = av.y;
        As[ac + 2][ar] = av.z;
        As[ac + 3][ar] = av.w;
        *(float4*)&Bs[bk][bc] = bv;
        __syncthreads();
#pragma unroll
        for (int kk = 0; kk < 16; kk++) {
            float4 a = *(const float4*)&As[kk][ty << 2];
            float4 b = *(const float4*)&Bs[kk][tx << 2];
            acc[0][0] += a.x * b.x; acc[0][1] += a.x * b.y; acc[0][2] += a.x * b.z; acc[0][3] += a.x * b.w;
            acc[1][0] += a.y * b.x; acc[1][1] += a.y * b.y; acc[1][2] += a.y * b.z; acc[1][3] += a.y * b.w;
            acc[2][0] += a.z * b.x; acc[2][1] += a.z * b.y; acc[2][2] += a.z * b.z; acc[2][3] += a.z * b.w;
            acc[3][0] += a.w * b.x; acc[3][1] += a.w * b.y; acc[3][2] += a.w * b.z; acc[3][3] += a.w * b.w;
        }
        __syncthreads();
    }

    float4 bv4 = make_float4(0.f, 0.f, 0.f, 0.f);
    if (bias) bv4 = *(const float4*)&bias[n0 + (tx << 2)];
#pragma unroll
    for (int u = 0; u < 4; u++) {
        int row = m0 + (ty << 2) + u;
        float4 o = make_float4(acc[u][0] + bv4.x, acc[u][1] + bv4.y,
                               acc[u][2] + bv4.z, acc[u][3] + bv4.w);
        *(float4*)&C[(size_t)row * N + n0 + (tx << 2)] = o;
    }
}

// ---------------------------------------------------------------------------
// Bias-fold dots, PRESCALED by 1/8, stored HEAD-MAJOR:
//   cbk[(h*B + b)*T + t]  = 0.125 * content_bias[h] . k[b,t,h,:]
//   rbrk[h*2T + m]        = 0.125 * relative_bias[h] . relk[m,h,:]
// ---------------------------------------------------------------------------
__global__ __launch_bounds__(256) void bias_dots_kernel(
    const float* __restrict__ kmat, const float* __restrict__ relk,
    const float* __restrict__ cb, const float* __restrict__ rb,
    float* __restrict__ cbk, float* __restrict__ rbrk) {
    int idx = blockIdx.x * 256 + threadIdx.x;
    if (idx < BB * TT * HH) {
        int h = idx & (HH - 1);
        int bt = idx >> 3;                 // b*T + t
        int b = bt >> 11, t = bt & (TT - 1);
        const float* kp  = kmat + (size_t)idx * DK;
        const float* cbp = cb + h * DK;
        float s = 0.f;
#pragma unroll
        for (int d = 0; d < DK; d++) s += cbp[d] * kp[d];
        cbk[((size_t)h * BB + b) * TT + t] = s * 0.125f;
    } else {
        int i2 = idx - BB * TT * HH;       // m*H + h
        int h = i2 & (HH - 1);
        int m = i2 >> 3;
        const float* rp  = relk + (size_t)i2 * DK;
        const float* rbp = rb + h * DK;
        float s = 0.f;
#pragma unroll
        for (int d = 0; d < DK; d++) s += rbp[d] * rp[d];
        rbrk[(size_t)h * (2 * TT) + m] = s * 0.125f;
    }
}

// ---------------------------------------------------------------------------
// Prepack fp32 32x64 tiles into swizzled hi/lo bf16 granule layout (8 KB/tile,
// hi at [0,4KB), lo at [4,8KB)). The attn kernel DMA-copies these into LDS.
//   mode 0: K tiles   (bid: b=bid>>9, h=(bid>>6)&7, jt=bid&63), B-frag layout
//   mode 1: R chunks  (bid: h=bid>>7, cidx=bid&127),            B-frag layout
//   mode 2: V tiles   (K-style bid), transposed V-frag layout
// K/R granule: g = nt*128 + n*8 + ((4s+kq+5n)&7)  [row n of 16, nt=row>>4,
//              d = s*32+kq*8+e]   -> frag read is phase-conflict-free.
// V granule:   g = ntd*64 + n*4 + ((kq+(n>>1))&3) [col d=ntd*16+n, j=kq*8+e]
// ---------------------------------------------------------------------------
__global__ __launch_bounds__(256) void prepack_kernel(
    const float* __restrict__ src, u16* __restrict__ dst, int mode) {
    __shared__ float tf[32][68];
    const int bid = blockIdx.x, tid = threadIdx.x;
    size_t soff;
    if (mode == 1) soff = ((size_t)(bid & 127) * 256 + (size_t)(bid >> 7)) * 64;
    else soff = ((size_t)(bid >> 9) * 2048 + (size_t)(bid & 63) * 32) * 512
                + (size_t)((bid >> 6) & 7) * 64;
    u16* dt = dst + (size_t)bid * 4096;
    const int r = tid >> 3, f = tid & 7;
    const float* p = src + soff + (size_t)r * 512 + (size_t)f * 8;
    float4 a  = *(const float4*)p;
    float4 b4 = *(const float4*)(p + 4);
    if (mode == 2) {
        *(float4*)&tf[r][f * 8]     = a;
        *(float4*)&tf[r][f * 8 + 4] = b4;
        __syncthreads();
        const int d = tid >> 2, kq = tid & 3;
        u32 hw[4], lw[4];
#pragma unroll
        for (int e = 0; e < 4; e++) {
            u16 h0, l0, h1, l1;
            split2(tf[kq * 8 + 2 * e][d], h0, l0);
            split2(tf[kq * 8 + 2 * e + 1][d], h1, l1);
            hw[e] = (u32)h0 | ((u32)h1 << 16);
            lw[e] = (u32)l0 | ((u32)l1 << 16);
        }
        const int n = d & 15;
        const int g = (d >> 4) * 64 + n * 4 + ((kq + (n >> 1)) & 3);
        *(uint4*)(dt + g * 8)        = make_uint4(hw[0], hw[1], hw[2], hw[3]);
        *(uint4*)(dt + 2048 + g * 8) = make_uint4(lw[0], lw[1], lw[2], lw[3]);
    } else {
        float xs[8] = {a.x, a.y, a.z, a.w, b4.x, b4.y, b4.z, b4.w};
        u32 hw[4], lw[4];
#pragma unroll
        for (int e = 0; e < 4; e++) {
            u16 h0, l0, h1, l1;
            split2(xs[2 * e], h0, l0);
            split2(xs[2 * e + 1], h1, l1);
            hw[e] = (u32)h0 | ((u32)h1 << 16);
            lw[e] = (u32)l0 | ((u32)l1 << 16);
        }
        const int s = f >> 2, kq = f & 3, nt = r >> 4, n = r & 15;
        const int g = nt * 128 + n * 8 + ((4 * s + kq + 5 * n) & 7);
        *(uint4*)(dt + g * 8)        = make_uint4(hw[0], hw[1], hw[2], hw[3]);
        *(uint4*)(dt + 2048 + g * 8) = make_uint4(lw[0], lw[1], lw[2], lw[3]);
    }
}

// ---------------------------------------------------------------------------
// MFMA flash attention with Transformer-XL rel-shift, bf16 hi/lo emulation.
// Block = (b, h, 64 Q rows), 4 waves, wave w owns rows 16w..16w+15.
// blockIdx swizzle: h in LOW bits -> all blocks of one head land on one XCD
// (round-robin % 8), per-XCD working set ~3 MB < 4 MB L2.
//
// rel2 ring in registers H[8][4] (y = T+j diagonal layout, see R3 notes).
// K/V/R tiles arrive prepacked; staging = global_load_lds DMA (no VGPRs!)
// into double-buffered LDS halves; one barrier per iteration; loads for
// jt+1 are in flight during all of jt's compute.
// ---------------------------------------------------------------------------
#define MRG(W) { \
    H[(P2 + W) & 7][r]     = cy ? H[(P2 + W) & 7][r] : v0; \
    H[(P2 + W + 1) & 7][r] = cy ? v0 : v1; \
    H[(P2 + W + 2) & 7][r] = cy ? v1 : H[(P2 + W + 2) & 7][r]; }

__global__ __launch_bounds__(256, 2) void attn_mfma_kernel(
    const float* __restrict__ q, const u16* __restrict__ Kpk,
    const u16* __restrict__ Vpk, const u16* __restrict__ Rpk,
    const float* __restrict__ cbk, const float* __restrict__ rbrk,
    float* __restrict__ attn_out) {
    __shared__ __align__(16) u16 Stage[2][12288];   // [half][ K | V | R ] 24 KB each
    __shared__ u32 Pbuf[4 * 544];

    const int tid = threadIdx.x;
    const int w = tid >> 6, lane = tid & 63, quad = lane >> 4, c = lane & 15;
    const int bx = blockIdx.x;
    const int h = bx & 7, b = (bx >> 3) & 1, it0 = bx >> 4;   // h in low bits
    const int i0 = it0 * 64;
    const size_t bh_off = (size_t)b * TT * DD + (size_t)h * DK;

    // ---- Q A-frags (hi/lo), prescaled 1/8; row = i0+16w+c, k = 32s+8quad+j
    frag_u qh[2], ql[2];
    {
        const float* qrow = q + bh_off + (size_t)(i0 + 16 * w + c) * DD;
#pragma unroll
        for (int s = 0; s < 2; s++) {
            int d0 = s * 32 + quad * 8;
            float4 a  = *(const float4*)(qrow + d0);
            float4 b4 = *(const float4*)(qrow + d0 + 4);
            float xs[8] = {a.x, a.y, a.z, a.w, b4.x, b4.y, b4.z, b4.w};
#pragma unroll
            for (int j2 = 0; j2 < 8; j2++)
                split2(xs[j2] * 0.125f, qh[s].u[j2], ql[s].u[j2]);
        }
    }

    const u16* Ktiles  = Kpk + (size_t)(b * HH + h) * 64 * 4096;
    const u16* Vtiles  = Vpk + (size_t)(b * HH + h) * 64 * 4096;
    const u16* Rchunks = Rpk + (size_t)h * 128 * 4096;
    const float* rbrk_h = rbrk + (size_t)h * (2 * TT);
    const float* cbk_h  = cbk + ((size_t)h * BB + b) * TT;

    float H[8][4];
#pragma unroll
    for (int s = 0; s < 8; s++)
#pragma unroll
        for (int r = 0; r < 4; r++) H[s][r] = 0.f;

    auto read_kr = [&](const u16* reg, int nt, int s, bf16x8& fh, bf16x8& fl) {
        int g = (nt << 7) + (c << 3) + (((s << 2) + quad + 5 * c) & 7);
        fh = *(const bf16x8*)(reg + g * 8);
        fl = *(const bf16x8*)(reg + 2048 + g * 8);
    };
    auto read_v = [&](const u16* Vb, int ntd, bf16x8& fh, bf16x8& fl) {
        int g = ntd * 64 + c * 4 + ((quad + (c >> 1)) & 3);
        fh = *(const bf16x8*)(Vb + g * 8);
        fl = *(const bf16x8*)(Vb + 2048 + g * 8);
    };

    const int k0c = (TT - i0 - 63) >> 5;   // (TT-i0-63) % 32 == 1

    // DMA-stage tiles for iteration jn into Stage[half]: 24 chunks of 1 KB,
    // wave w issues chunks [6w, 6w+6). Chunk ch: region ch>>3 (0=K,1=V,2=R),
    // offset (ch&7)*1KB. Wave-uniform LDS base; per-lane global = +lane*16B.
    auto stage_async = [&](int jn, int half) {
        const u16* Ks = Ktiles + (size_t)jn * 4096;
        const u16* Vs = Vtiles + (size_t)jn * 4096;
        int cidx = k0c + jn + 2; if (cidx > 127) cidx = 127;
        const u16* Rs = Rchunks + (size_t)cidx * 4096;
        u16* dst = Stage[half];
#pragma unroll
        for (int u = 0; u < 6; u++) {
            int ch = w * 6 + u;
            int rg = ch >> 3;
            int of = (ch & 7) << 9;       // u16 units, 512 u16 = 1 KB
            const u16* g = (rg == 0 ? Ks : rg == 1 ? Vs : Rs) + of + lane * 8;
            u16* l = dst + (rg << 12) + of;
            load_lds16(g, l);
        }
    };

    // produce rel2 chunk (32 m values) for this wave's 16 rows from Rb, then
    // redistribute into register ring H (y-diagonal layout). rbv = prescaled
    // rbrk values for this chunk (lane c -> m = cidx*32 + ntp*16 + c).
    auto produce = [&](auto PC, const u16* Rb, float rbv0, float rbv1) {
        constexpr int P2 = (2 * decltype(PC)::v) & 7;
        f32x4 rc[2];
#pragma unroll
        for (int ntp = 0; ntp < 2; ntp++) {
            f32x4 acc = {0.f, 0.f, 0.f, 0.f};
#pragma unroll
            for (int s = 0; s < 2; s++) {
                bf16x8 fh, fl;
                read_kr(Rb, ntp, s, fh, fl);
                acc = __builtin_amdgcn_mfma_f32_16x16x32_bf16(qh[s].f, fh, acc, 0, 0, 0);
                acc = __builtin_amdgcn_mfma_f32_16x16x32_bf16(qh[s].f, fl, acc, 0, 0, 0);
                acc = __builtin_amdgcn_mfma_f32_16x16x32_bf16(ql[s].f, fh, acc, 0, 0, 0);
            }
            float rbv = ntp ? rbv1 : rbv0;
#pragma unroll
            for (int r = 0; r < 4; r++) acc[r] += rbv;
            rc[ntp] = acc;
        }
#pragma unroll
        for (int r = 0; r < 4; r++) {
            int srcl = (quad << 4) + ((c - 4 * quad - r) & 15);
            float v0 = __uint_as_float(__builtin_amdgcn_ds_bpermute(
                srcl << 2, __float_as_uint(rc[0][r])));
            float v1 = __uint_as_float(__builtin_amdgcn_ds_bpermute(
                srcl << 2, __float_as_uint(rc[1][r])));
            bool cy = c < (4 * quad + r);
            if (w == 0)      MRG(0)
            else if (w == 1) MRG(1)
            else if (w == 2) MRG(2)
            else             MRG(3)
        }
    };

    // ---- prologue: rel2 chunks k0c (virtual jt=-2, P2=4), k0c+1 (P2=6) ----
    {
        const uint4* rs = (const uint4*)(Rchunks + (size_t)k0c * 4096);
        uint4* rb = (uint4*)(Stage[0] + 8192);
        rb[tid] = rs[tid]; rb[tid + 256] = rs[tid + 256];
    }
    __syncthreads();
    produce(ic_t<2>{}, Stage[0] + 8192,
            rbrk_h[k0c * 32 + c], rbrk_h[k0c * 32 + 16 + c]);
    __syncthreads();
    {
        const uint4* rs = (const uint4*)(Rchunks + (size_t)(k0c + 1) * 4096);
        uint4* rb = (uint4*)(Stage[0] + 8192);
        rb[tid] = rs[tid]; rb[tid + 256] = rs[tid + 256];
    }
    __syncthreads();
    produce(ic_t<3>{}, Stage[0] + 8192,
            rbrk_h[(k0c + 1) * 32 + c], rbrk_h[(k0c + 1) * 32 + 16 + c]);
    __syncthreads();          // ring reads done before DMA overwrites Stage[0]
    stage_async(0, 0);

    float m_run[4], l_run[4];
    f32x4 o[4];
#pragma unroll
    for (int r = 0; r < 4; r++) { m_run[r] = -INFINITY; l_run[r] = 0.f; }
#pragma unroll
    for (int nt = 0; nt < 4; nt++) o[nt] = (f32x4){0.f, 0.f, 0.f, 0.f};

    auto body = [&](auto PC, int jt0) {
        constexpr int P = decltype(PC)::v;
        constexpr int half = P & 1;             // jt0 % 4 == 0 -> (jt&1) == (P&1)
        const int jt = jt0 + P;
        const int j0 = jt * 32;
        const u16* Kb = Stage[half];
        const u16* Vb = Stage[half] + 4096;
        const u16* Rb = Stage[half] + 8192;
        __syncthreads();   // drains this half's DMA; prior reads of other half done

        // scalar loads for this iter, issued BEFORE the next DMA batch
        int cidx = k0c + jt + 2; if (cidx > 127) cidx = 127;
        float rbv0 = rbrk_h[cidx * 32 + c];
        float rbv1 = rbrk_h[cidx * 32 + 16 + c];
        float cbv0 = cbk_h[j0 + c];
        float cbv1 = cbk_h[j0 + 16 + c];

        if (jt < 63) stage_async(jt + 1, 1 - half);

        produce(PC, Rb, rbv0, rbv1);

        // ---- S = QK (MFMA) + rel (register!) + cbk ----
        float sv[2][4];
#pragma unroll
        for (int nt = 0; nt < 2; nt++) {
            f32x4 sc = {0.f, 0.f, 0.f, 0.f};
#pragma unroll
            for (int s = 0; s < 2; s++) {
                bf16x8 fh, fl;
                read_kr(Kb, nt, s, fh, fl);
                sc = __builtin_amdgcn_mfma_f32_16x16x32_bf16(qh[s].f, fh, sc, 0, 0, 0);
                sc = __builtin_amdgcn_mfma_f32_16x16x32_bf16(qh[s].f, fl, sc, 0, 0, 0);
                sc = __builtin_amdgcn_mfma_f32_16x16x32_bf16(ql[s].f, fh, sc, 0, 0, 0);
            }
            float cbv = nt ? cbv1 : cbv0;
#pragma unroll
            for (int r = 0; r < 4; r++)
                sv[nt][r] = sc[r] + H[(2 * P + nt) & 7][r] + cbv;
        }

        // ---- online softmax (16 lanes per row) + P write (packed u32) ----
#pragma unroll
        for (int r = 0; r < 4; r++) {
            float tm = fmaxf(sv[0][r], sv[1][r]);
#pragma unroll
            for (int off = 1; off < 16; off <<= 1) tm = fmaxf(tm, __shfl_xor(tm, off));
            float mnew = fmaxf(m_run[r], tm);
            float al = __expf(m_run[r] - mnew);
            float p0 = __expf(sv[0][r] - mnew);
            float p1 = __expf(sv[1][r] - mnew);
            float ps = p0 + p1;
#pragma unroll
            for (int off = 1; off < 16; off <<= 1) ps += __shfl_xor(ps, off);
            l_run[r] = l_run[r] * al + ps;
            m_run[r] = mnew;
#pragma unroll
            for (int nt = 0; nt < 4; nt++) o[nt][r] *= al;
            u32* pb = Pbuf + w * 544 + (quad * 4 + r) * 34;
            pb[c]      = split_pack(p0);
            pb[16 + c] = split_pack(p1);
        }

        // ---- O += P @ V (hi/lo) ----
        frag_u ph, pl;
        {
            const u32* pb = Pbuf + w * 544 + c * 34 + quad * 8;
            uint2 r0 = *(const uint2*)(pb);
            uint2 r1 = *(const uint2*)(pb + 2);
            uint2 r2 = *(const uint2*)(pb + 4);
            uint2 r3 = *(const uint2*)(pb + 6);
            u32 pk[8] = {r0.x, r0.y, r1.x, r1.y, r2.x, r2.y, r3.x, r3.y};
#pragma unroll
            for (int j2 = 0; j2 < 8; j2++) {
                ph.u[j2] = (u16)(pk[j2] >> 16);
                pl.u[j2] = (u16)(pk[j2] & 0xffffu);
            }
        }
#pragma unroll
        for (int ntd = 0; ntd < 4; ntd++) {
            bf16x8 vh, vl;
            read_v(Vb, ntd, vh, vl);
            o[ntd] = __builtin_amdgcn_mfma_f32_16x16x32_bf16(ph.f, vh, o[ntd], 0, 0, 0);
            o[ntd] = __builtin_amdgcn_mfma_f32_16x16x32_bf16(ph.f, vl, o[ntd], 0, 0, 0);
            o[ntd] = __builtin_amdgcn_mfma_f32_16x16x32_bf16(pl.f, vh, o[ntd], 0, 0, 0);
        }
    };

    for (int jt0 = 0; jt0 < TT / 32; jt0 += 4) {
        body(ic_t<0>{}, jt0);
        body(ic_t<1>{}, jt0);
        body(ic_t<2>{}, jt0);
        body(ic_t<3>{}, jt0);
    }

    // ---- epilogue: normalize, store [B,T,H*Dk] ----
#pragma unroll
    for (int nt = 0; nt < 4; nt++) {
#pragma unroll
        for (int r = 0; r < 4; r++) {
            int row16 = quad * 4 + r;
            int i_abs = i0 + 16 * w + row16;
            attn_out[((size_t)b * TT + i_abs) * DD + h * DK + nt * 16 + c] =
                o[nt][r] / l_run[r];
        }
    }
}

// ---------------------------------------------------------------------------
extern "C" void kernel_launch(void* const* d_in, const int* in_sizes, int n_in,
                              void* d_out, int out_size, void* d_ws, size_t ws_size,
                              hipStream_t stream) {
    const float* query  = (const float*)d_in[0];
    const float* key_in = (const float*)d_in[1];
    const float* value  = (const float*)d_in[2];
    const float* Wq = (const float*)d_in[3];
    const float* bq = (const float*)d_in[4];
    const float* Wk = (const float*)d_in[5];
    const float* bk = (const float*)d_in[6];
    const float* Wv = (const float*)d_in[7];
    const float* bv = (const float*)d_in[8];
    const float* Wr = (const float*)d_in[9];
    const float* cb = (const float*)d_in[10];
    const float* rb = (const float*)d_in[11];
    const float* Wo = (const float*)d_in[12];
    const float* bo = (const float*)d_in[13];
    float* out = (float*)d_out;

    float* ws = (float*)d_ws;
    const size_t SL = (size_t)MM * DD;        // 2097152 floats per slot
    float* qb    = ws;                        // fp32 Q [B,T,H,Dk]
    float* kb    = ws + SL;                   // fp32 K (consumed, then holds Rpk)
    float* vb    = ws + 2 * SL;               // fp32 V (consumed, then holds Kpk)
    float* relk  = ws + 3 * SL;               // fp32 relK [2T,H,Dk]
    float* attnv = ws + 4 * SL;               // attn output (pe aliased here first)
    float* pe    = attnv;                     // pe consumed before attnv written
    u16*   Vpk   = (u16*)(ws + 5 * SL);       // packed V tiles (8 MB)
    u16*   Kpk   = (u16*)vb;                  // packed K tiles (8 MB)
    u16*   Rpk   = (u16*)kb;                  // packed R chunks (8 MB)
    float* cbk   = ws + 6 * SL;               // [H*B*T]
    float* rbrk  = cbk + BB * TT * HH;        // [H*2T]

    const dim3 gemm_grid(DD / 64, MM / 64);   // (8, 64)

    pe_kernel<<<(2 * TT * DD) / 256, 256, 0, stream>>>(pe);
    gemm_bias_kernel<<<gemm_grid, 256, 0, stream>>>(pe, Wr, nullptr, relk, MM, DD, DD);
    gemm_bias_kernel<<<gemm_grid, 256, 0, stream>>>(query,  Wq, bq, qb, MM, DD, DD);
    gemm_bias_kernel<<<gemm_grid, 256, 0, stream>>>(key_in, Wk, bk, kb, MM, DD, DD);
    gemm_bias_kernel<<<gemm_grid, 256, 0, stream>>>(value,  Wv, bv, vb, MM, DD, DD);
    bias_dots_kernel<<<(BB * TT * HH + 2 * TT * HH) / 256, 256, 0, stream>>>(
        kb, relk, cb, rb, cbk, rbrk);
    // prepack order matters (aliasing): V first (frees vb), then K (-> vb),
    // then R (-> kb, after K consumed kb).
    prepack_kernel<<<1024, 256, 0, stream>>>(vb, Vpk, 2);
    prepack_kernel<<<1024, 256, 0, stream>>>(kb, Kpk, 0);
    prepack_kernel<<<1024, 256, 0, stream>>>(relk, Rpk, 1);
    attn_mfma_kernel<<<BB * HH * (TT / 64), 256, 0, stream>>>(
        qb, Kpk, Vpk, Rpk, cbk, rbrk, attnv);
    gemm_bias_kernel<<<gemm_grid, 256, 0, stream>>>(attnv, Wo, bo, out, MM, DD, DD);
}

// Round 6
// 486.435 us; speedup vs baseline: 1.6633x; 1.1152x over previous
//
#include <hip/hip_runtime.h>
#include <math.h>

// Problem constants: B=2, T=2048, H=8, Dk=64, D=512
#define BB 2
#define TT 2048
#define HH 8
#define DK 64
#define DD 512
#define MM (BB * TT)

typedef unsigned int u32;
typedef unsigned short u16;
typedef __bf16 bf16x8 __attribute__((ext_vector_type(8)));
typedef float f32x4 __attribute__((ext_vector_type(4)));

union frag_u { bf16x8 f; u16 u[8]; u32 w[4]; };

// fp32 -> bf16 hi + bf16 lo (RNE both); x ~= hi + lo to ~2^-20 rel.
__device__ __forceinline__ void split2(float x, u16& h, u16& l) {
    u32 u = __float_as_uint(x);
    u32 hi = (u + 0x7fffu + ((u >> 16) & 1u)) >> 16;
    float hif = __uint_as_float(hi << 16);
    float lof = x - hif;                       // exact
    u32 ul = __float_as_uint(lof);
    u32 lo = (ul + 0x7fffu + ((ul >> 16) & 1u)) >> 16;
    h = (u16)hi; l = (u16)lo;
}
__device__ __forceinline__ u32 split_pack(float x) {
    u16 h, l; split2(x, h, l);
    return ((u32)h << 16) | (u32)l;
}

// async global->LDS, 16B per lane, LDS dest = wave-uniform base + lane*16
__device__ __forceinline__ void load_lds16(const void* g, void* l) {
    __builtin_amdgcn_global_load_lds(
        (const __attribute__((address_space(1))) void*)g,
        (__attribute__((address_space(3))) void*)l, 16, 0, 0);
}

// ---------------------------------------------------------------------------
// Sinusoid position encoding (fp64 math to match numpy float64 path).
// ---------------------------------------------------------------------------
__global__ __launch_bounds__(256) void pe_kernel(float* __restrict__ pe) {
    int idx = blockIdx.x * 256 + threadIdx.x;
    int m   = idx >> 9;
    int col = idx & 511;
    int j   = col & 255;
    double inv_freq = exp((double)(-2 * j) * (9.210340371976184 / 512.0));
    double ang = (double)(TT - m) * inv_freq;
    pe[idx] = (col < 256) ? (float)sin(ang) : (float)cos(ang);
}

// ---------------------------------------------------------------------------
// Tiled fp32 GEMM + bias. BM=BN=64, BK=16, 256 thr, 4x4 micro-tile.
// ---------------------------------------------------------------------------
__global__ __launch_bounds__(256) void gemm_bias_kernel(
    const float* __restrict__ A, const float* __restrict__ W,
    const float* __restrict__ bias, float* __restrict__ C,
    int M, int N, int K) {
    __shared__ float As[16][68];
    __shared__ float Bs[16][68];

    const int tid = threadIdx.x;
    const int n0 = blockIdx.x * 64;
    const int m0 = blockIdx.y * 64;
    const int tx = tid & 15;
    const int ty = tid >> 4;

    const int ar = tid >> 2;
    const int ac = (tid & 3) << 2;
    const int bk = tid >> 4;
    const int bc = (tid & 15) << 2;

    float acc[4][4] = {};

    for (int k0 = 0; k0 < K; k0 += 16) {
        float4 av = *(const float4*)&A[(size_t)(m0 + ar) * K + k0 + ac];
        float4 bv = *(const float4*)&W[(size_t)(k0 + bk) * N + n0 + bc];
        As[ac + 0][ar] = av.x;
        As[ac + 1][ar] = av.y;
        As[ac + 2][ar] = av.z;
        As[ac + 3][ar] = av.w;
        *(float4*)&Bs[bk][bc] = bv;
        __syncthreads();
#pragma unroll
        for (int kk = 0; kk < 16; kk++) {
            float4 a = *(const float4*)&As[kk][ty << 2];
            float4 b = *(const float4*)&Bs[kk][tx << 2];
            acc[0][0] += a.x * b.x; acc[0][1] += a.x * b.y; acc[0][2] += a.x * b.z; acc[0][3] += a.x * b.w;
            acc[1][0] += a.y * b.x; acc[1][1] += a.y * b.y; acc[1][2] += a.y * b.z; acc[1][3] += a.y * b.w;
            acc[2][0] += a.z * b.x; acc[2][1] += a.z * b.y; acc[2][2] += a.z * b.z; acc[2][3] += a.z * b.w;
            acc[3][0] += a.w * b.x; acc[3][1] += a.w * b.y; acc[3][2] += a.w * b.z; acc[3][3] += a.w * b.w;
        }
        __syncthreads();
    }

    float4 bv4 = make_float4(0.f, 0.f, 0.f, 0.f);
    if (bias) bv4 = *(const float4*)&bias[n0 + (tx << 2)];
#pragma unroll
    for (int u = 0; u < 4; u++) {
        int row = m0 + (ty << 2) + u;
        float4 o = make_float4(acc[u][0] + bv4.x, acc[u][1] + bv4.y,
                               acc[u][2] + bv4.z, acc[u][3] + bv4.w);
        *(float4*)&C[(size_t)row * N + n0 + (tx << 2)] = o;
    }
}

// ---------------------------------------------------------------------------
// Bias-fold dots, PRESCALED by 1/8, stored HEAD-MAJOR:
//   cbk[(h*B + b)*T + t]  = 0.125 * content_bias[h] . k[b,t,h,:]
//   rbrk[h*2T + m]        = 0.125 * relative_bias[h] . relk[m,h,:]
// ---------------------------------------------------------------------------
__global__ __launch_bounds__(256) void bias_dots_kernel(
    const float* __restrict__ kmat, const float* __restrict__ relk,
    const float* __restrict__ cb, const float* __restrict__ rb,
    float* __restrict__ cbk, float* __restrict__ rbrk) {
    int idx = blockIdx.x * 256 + threadIdx.x;
    if (idx < BB * TT * HH) {
        int h = idx & (HH - 1);
        int bt = idx >> 3;                 // b*T + t
        int b = bt >> 11, t = bt & (TT - 1);
        const float* kp  = kmat + (size_t)idx * DK;
        const float* cbp = cb + h * DK;
        float s = 0.f;
#pragma unroll
        for (int d = 0; d < DK; d++) s += cbp[d] * kp[d];
        cbk[((size_t)h * BB + b) * TT + t] = s * 0.125f;
    } else {
        int i2 = idx - BB * TT * HH;       // m*H + h
        int h = i2 & (HH - 1);
        int m = i2 >> 3;
        const float* rp  = relk + (size_t)i2 * DK;
        const float* rbp = rb + h * DK;
        float s = 0.f;
#pragma unroll
        for (int d = 0; d < DK; d++) s += rbp[d] * rp[d];
        rbrk[(size_t)h * (2 * TT) + m] = s * 0.125f;
    }
}

// ---------------------------------------------------------------------------
// Prepack fp32 32x64 tiles into swizzled hi/lo bf16 granule layout (8 KB/tile,
// hi at [0,4KB), lo at [4,8KB)).
//   mode 0: K tiles   (bid: b=bid>>9, h=(bid>>6)&7, jt=bid&63), B-frag layout
//   mode 1: R chunks  (bid: h=bid>>7, cidx=bid&127),            B-frag layout
//   mode 2: V tiles   (K-style bid), transposed V-frag layout
// K/R granule: g = nt*128 + n*8 + ((4s+kq+5n)&7)  [row n of 16, nt=row>>4,
//              d = s*32+kq*8+e]   -> frag read is phase-conflict-free.
// V granule:   g = ntd*64 + n*4 + ((kq+(n>>1))&3) [col d=ntd*16+n, j=kq*8+e]
// ---------------------------------------------------------------------------
__global__ __launch_bounds__(256) void prepack_kernel(
    const float* __restrict__ src, u16* __restrict__ dst, int mode) {
    __shared__ float tf[32][68];
    const int bid = blockIdx.x, tid = threadIdx.x;
    size_t soff;
    if (mode == 1) soff = ((size_t)(bid & 127) * 256 + (size_t)(bid >> 7)) * 64;
    else soff = ((size_t)(bid >> 9) * 2048 + (size_t)(bid & 63) * 32) * 512
                + (size_t)((bid >> 6) & 7) * 64;
    u16* dt = dst + (size_t)bid * 4096;
    const int r = tid >> 3, f = tid & 7;
    const float* p = src + soff + (size_t)r * 512 + (size_t)f * 8;
    float4 a  = *(const float4*)p;
    float4 b4 = *(const float4*)(p + 4);
    if (mode == 2) {
        *(float4*)&tf[r][f * 8]     = a;
        *(float4*)&tf[r][f * 8 + 4] = b4;
        __syncthreads();
        const int d = tid >> 2, kq = tid & 3;
        u32 hw[4], lw[4];
#pragma unroll
        for (int e = 0; e < 4; e++) {
            u16 h0, l0, h1, l1;
            split2(tf[kq * 8 + 2 * e][d], h0, l0);
            split2(tf[kq * 8 + 2 * e + 1][d], h1, l1);
            hw[e] = (u32)h0 | ((u32)h1 << 16);
            lw[e] = (u32)l0 | ((u32)l1 << 16);
        }
        const int n = d & 15;
        const int g = (d >> 4) * 64 + n * 4 + ((kq + (n >> 1)) & 3);
        *(uint4*)(dt + g * 8)        = make_uint4(hw[0], hw[1], hw[2], hw[3]);
        *(uint4*)(dt + 2048 + g * 8) = make_uint4(lw[0], lw[1], lw[2], lw[3]);
    } else {
        float xs[8] = {a.x, a.y, a.z, a.w, b4.x, b4.y, b4.z, b4.w};
        u32 hw[4], lw[4];
#pragma unroll
        for (int e = 0; e < 4; e++) {
            u16 h0, l0, h1, l1;
            split2(xs[2 * e], h0, l0);
            split2(xs[2 * e + 1], h1, l1);
            hw[e] = (u32)h0 | ((u32)h1 << 16);
            lw[e] = (u32)l0 | ((u32)l1 << 16);
        }
        const int s = f >> 2, kq = f & 3, nt = r >> 4, n = r & 15;
        const int g = nt * 128 + n * 8 + ((4 * s + kq + 5 * n) & 7);
        *(uint4*)(dt + g * 8)        = make_uint4(hw[0], hw[1], hw[2], hw[3]);
        *(uint4*)(dt + 2048 + g * 8) = make_uint4(lw[0], lw[1], lw[2], lw[3]);
    }
}

// ---------------------------------------------------------------------------
// MFMA flash attention with Transformer-XL rel-shift, bf16 hi/lo emulation.
// Block = (b, h, 64 Q rows), 4 waves, wave w owns rows 16w..16w+15.
// blockIdx swizzle: h in LOW bits -> per-XCD working set (K+V for one h both
// b, plus 1 MB R) ~3 MB < 4 MB L2.
//
// rel2 ring: back to the R2-proven per-wave LDS ring (4 slots keyed cidx&3,
// rows x 35 pad) -- runtime-indexed LDS, no register ring, no bpermute, no
// divergent merges (this was R3/R4's scratch-spill source). produce() reads
// its R frags DIRECTLY from global (prepacked, L2-resident via h-swizzle).
// K/V tiles: double-buffered global_load_lds DMA; ONE barrier per body;
// next tiles are in flight during the whole compute phase.
// ---------------------------------------------------------------------------
__global__ __launch_bounds__(256, 2) void attn_mfma_kernel(
    const float* __restrict__ q, const u16* __restrict__ Kpk,
    const u16* __restrict__ Vpk, const u16* __restrict__ Rpk,
    const float* __restrict__ cbk, const float* __restrict__ rbrk,
    float* __restrict__ attn_out) {
    __shared__ __align__(16) u16 Stage[2][8192];   // [half][ K(4096) | V(4096) ]
    __shared__ float Ring[4 * 4 * 560];            // [wave][slot][16][35]
    __shared__ u32 Pbuf[4 * 544];                  // [wave][16][34]

    const int tid = threadIdx.x;
    const int w = tid >> 6, lane = tid & 63, quad = lane >> 4, c = lane & 15;
    const int bx = blockIdx.x;
    const int h = bx & 7, b = (bx >> 3) & 1, it0 = bx >> 4;   // h in low bits
    const int i0 = it0 * 64;
    const size_t bh_off = (size_t)b * TT * DD + (size_t)h * DK;

    // ---- Q A-frags (hi/lo), prescaled 1/8; row = i0+16w+c, k = 32s+8quad+j
    frag_u qh[2], ql[2];
    {
        const float* qrow = q + bh_off + (size_t)(i0 + 16 * w + c) * DD;
#pragma unroll
        for (int s = 0; s < 2; s++) {
            int d0 = s * 32 + quad * 8;
            float4 a  = *(const float4*)(qrow + d0);
            float4 b4 = *(const float4*)(qrow + d0 + 4);
            float xs[8] = {a.x, a.y, a.z, a.w, b4.x, b4.y, b4.z, b4.w};
#pragma unroll
            for (int j2 = 0; j2 < 8; j2++)
                split2(xs[j2] * 0.125f, qh[s].u[j2], ql[s].u[j2]);
        }
    }

    const u16* Ktiles  = Kpk + (size_t)(b * HH + h) * 64 * 4096;
    const u16* Vtiles  = Vpk + (size_t)(b * HH + h) * 64 * 4096;
    const u16* Rchunks = Rpk + (size_t)h * 128 * 4096;
    const float* rbrk_h = rbrk + (size_t)h * (2 * TT);
    const float* cbk_h  = cbk + ((size_t)h * BB + b) * TT;

    auto read_kr = [&](const u16* reg, int nt, int s, bf16x8& fh, bf16x8& fl) {
        int g = (nt << 7) + (c << 3) + (((s << 2) + quad + 5 * c) & 7);
        fh = *(const bf16x8*)(reg + g * 8);
        fl = *(const bf16x8*)(reg + 2048 + g * 8);
    };
    auto read_v = [&](const u16* Vb, int ntd, bf16x8& fh, bf16x8& fl) {
        int g = ntd * 64 + c * 4 + ((quad + (c >> 1)) & 3);
        fh = *(const bf16x8*)(Vb + g * 8);
        fl = *(const bf16x8*)(Vb + 2048 + g * 8);
    };

    const int k0c = (TT - i0 - 63) >> 5;   // in [0, 62]; chunks used: k0c..k0c+65<=127

    // produce rel2 chunk cidx for this wave's 16 rows into LDS ring slot
    // cidx&3 (rbrk folded in). R frags come straight from global (L2-hot).
    auto produce = [&](int cidx) {
        const u16* Rc = Rchunks + (size_t)cidx * 4096;
        float* ringw = Ring + (w * 4 + (cidx & 3)) * 560;
#pragma unroll
        for (int ntp = 0; ntp < 2; ntp++) {
            f32x4 acc = {0.f, 0.f, 0.f, 0.f};
#pragma unroll
            for (int s = 0; s < 2; s++) {
                int g = (ntp << 7) + (c << 3) + (((s << 2) + quad + 5 * c) & 7);
                bf16x8 fh = *(const bf16x8*)(Rc + g * 8);
                bf16x8 fl = *(const bf16x8*)(Rc + 2048 + g * 8);
                acc = __builtin_amdgcn_mfma_f32_16x16x32_bf16(qh[s].f, fh, acc, 0, 0, 0);
                acc = __builtin_amdgcn_mfma_f32_16x16x32_bf16(qh[s].f, fl, acc, 0, 0, 0);
                acc = __builtin_amdgcn_mfma_f32_16x16x32_bf16(ql[s].f, fh, acc, 0, 0, 0);
            }
            float rbv = rbrk_h[cidx * 32 + ntp * 16 + c];
            int mpos = ntp * 16 + c;
#pragma unroll
            for (int r = 0; r < 4; r++)
                ringw[(quad * 4 + r) * 35 + mpos] = acc[r] + rbv;
        }
    };

    // DMA K+V tiles for iteration jn into Stage[half]: 16 chunks of 1 KB,
    // wave w issues 4. LDS dest wave-uniform; global per-lane = +lane*16B.
    auto stage_async = [&](int jn, int half) {
        const u16* Ks = Ktiles + (size_t)jn * 4096;
        const u16* Vs = Vtiles + (size_t)jn * 4096;
        u16* dst = Stage[half];
#pragma unroll
        for (int u = 0; u < 4; u++) {
            int ch = w * 4 + u;
            int rg = ch >> 3;                 // 0 = K, 1 = V
            int of = (ch & 7) << 9;           // 512 u16 = 1 KB
            const u16* g = (rg ? Vs : Ks) + of + lane * 8;
            load_lds16(g, dst + (rg << 12) + of);
        }
    };

    // ---- prologue: DMA tiles for jt=0; rel2 chunks k0c, k0c+1 (per-wave) ----
    stage_async(0, 0);
    produce(k0c);
    produce(k0c + 1);

    float m_run[4], l_run[4];
    f32x4 o[4];
#pragma unroll
    for (int r = 0; r < 4; r++) { m_run[r] = -INFINITY; l_run[r] = 0.f; }
#pragma unroll
    for (int nt = 0; nt < 4; nt++) o[nt] = (f32x4){0.f, 0.f, 0.f, 0.f};

    for (int jt = 0; jt < TT / 32; jt++) {
        const int j0 = jt * 32;
        const int half = jt & 1;
        const u16* Kb = Stage[half];
        const u16* Vb = Stage[half] + 4096;
        // Barrier: (a) drains this half's DMA (vmcnt(0) at barrier),
        // (b) orders prior body's reads of the other half before its refill.
        __syncthreads();
        if (jt < TT / 32 - 1) stage_async(jt + 1, 1 - half);

        produce(k0c + jt + 2);   // per-wave ring write; same-wave read below

        // ---- S = QK (MFMA) + ring rel gather + cbk ----
        const int mb0 = TT - i0 - 16 * w + j0;
        float cbv0 = cbk_h[j0 + c];
        float cbv1 = cbk_h[j0 + 16 + c];
        float sv[2][4];
#pragma unroll
        for (int nt = 0; nt < 2; nt++) {
            f32x4 sc = {0.f, 0.f, 0.f, 0.f};
#pragma unroll
            for (int s = 0; s < 2; s++) {
                bf16x8 fh, fl;
                read_kr(Kb, nt, s, fh, fl);
                sc = __builtin_amdgcn_mfma_f32_16x16x32_bf16(qh[s].f, fh, sc, 0, 0, 0);
                sc = __builtin_amdgcn_mfma_f32_16x16x32_bf16(qh[s].f, fl, sc, 0, 0, 0);
                sc = __builtin_amdgcn_mfma_f32_16x16x32_bf16(ql[s].f, fh, sc, 0, 0, 0);
            }
            int mc = mb0 + nt * 16 + c;
            float cbv = nt ? cbv1 : cbv0;
#pragma unroll
            for (int r = 0; r < 4; r++) {
                int row16 = quad * 4 + r;
                int m_abs = mc - row16;
                float rel = Ring[(w * 4 + ((m_abs >> 5) & 3)) * 560
                                 + row16 * 35 + (m_abs & 31)];
                sv[nt][r] = sc[r] + rel + cbv;
            }
        }

        // ---- online softmax (16 lanes per row) + P write (packed u32) ----
#pragma unroll
        for (int r = 0; r < 4; r++) {
            float tm = fmaxf(sv[0][r], sv[1][r]);
#pragma unroll
            for (int off = 1; off < 16; off <<= 1) tm = fmaxf(tm, __shfl_xor(tm, off));
            float mnew = fmaxf(m_run[r], tm);
            float al = __expf(m_run[r] - mnew);
            float p0 = __expf(sv[0][r] - mnew);
            float p1 = __expf(sv[1][r] - mnew);
            float ps = p0 + p1;
#pragma unroll
            for (int off = 1; off < 16; off <<= 1) ps += __shfl_xor(ps, off);
            l_run[r] = l_run[r] * al + ps;
            m_run[r] = mnew;
#pragma unroll
            for (int nt = 0; nt < 4; nt++) o[nt][r] *= al;
            u32* pb = Pbuf + w * 544 + (quad * 4 + r) * 34;
            pb[c]      = split_pack(p0);
            pb[16 + c] = split_pack(p1);
        }

        // ---- O += P @ V (hi/lo) ----
        frag_u ph, pl;
        {
            const u32* pb = Pbuf + w * 544 + c * 34 + quad * 8;
            uint2 r0 = *(const uint2*)(pb);
            uint2 r1 = *(const uint2*)(pb + 2);
            uint2 r2 = *(const uint2*)(pb + 4);
            uint2 r3 = *(const uint2*)(pb + 6);
            u32 pk[8] = {r0.x, r0.y, r1.x, r1.y, r2.x, r2.y, r3.x, r3.y};
#pragma unroll
            for (int j2 = 0; j2 < 8; j2++) {
                ph.u[j2] = (u16)(pk[j2] >> 16);
                pl.u[j2] = (u16)(pk[j2] & 0xffffu);
            }
        }
#pragma unroll
        for (int ntd = 0; ntd < 4; ntd++) {
            bf16x8 vh, vl;
            read_v(Vb, ntd, vh, vl);
            o[ntd] = __builtin_amdgcn_mfma_f32_16x16x32_bf16(ph.f, vh, o[ntd], 0, 0, 0);
            o[ntd] = __builtin_amdgcn_mfma_f32_16x16x32_bf16(ph.f, vl, o[ntd], 0, 0, 0);
            o[ntd] = __builtin_amdgcn_mfma_f32_16x16x32_bf16(pl.f, vh, o[ntd], 0, 0, 0);
        }
    }

    // ---- epilogue: normalize, store [B,T,H*Dk] ----
#pragma unroll
    for (int nt = 0; nt < 4; nt++) {
#pragma unroll
        for (int r = 0; r < 4; r++) {
            int row16 = quad * 4 + r;
            int i_abs = i0 + 16 * w + row16;
            attn_out[((size_t)b * TT + i_abs) * DD + h * DK + nt * 16 + c] =
                o[nt][r] / l_run[r];
        }
    }
}

// ---------------------------------------------------------------------------
extern "C" void kernel_launch(void* const* d_in, const int* in_sizes, int n_in,
                              void* d_out, int out_size, void* d_ws, size_t ws_size,
                              hipStream_t stream) {
    const float* query  = (const float*)d_in[0];
    const float* key_in = (const float*)d_in[1];
    const float* value  = (const float*)d_in[2];
    const float* Wq = (const float*)d_in[3];
    const float* bq = (const float*)d_in[4];
    const float* Wk = (const float*)d_in[5];
    const float* bk = (const float*)d_in[6];
    const float* Wv = (const float*)d_in[7];
    const float* bv = (const float*)d_in[8];
    const float* Wr = (const float*)d_in[9];
    const float* cb = (const float*)d_in[10];
    const float* rb = (const float*)d_in[11];
    const float* Wo = (const float*)d_in[12];
    const float* bo = (const float*)d_in[13];
    float* out = (float*)d_out;

    float* ws = (float*)d_ws;
    const size_t SL = (size_t)MM * DD;        // 2097152 floats per slot
    float* qb    = ws;                        // fp32 Q [B,T,H,Dk]
    float* kb    = ws + SL;                   // fp32 K (consumed, then holds Rpk)
    float* vb    = ws + 2 * SL;               // fp32 V (consumed, then holds Kpk)
    float* relk  = ws + 3 * SL;               // fp32 relK [2T,H,Dk]
    float* attnv = ws + 4 * SL;               // attn output (pe aliased here first)
    float* pe    = attnv;                     // pe consumed before attnv written
    u16*   Vpk   = (u16*)(ws + 5 * SL);       // packed V tiles (8 MB)
    u16*   Kpk   = (u16*)vb;                  // packed K tiles (8 MB)
    u16*   Rpk   = (u16*)kb;                  // packed R chunks (8 MB)
    float* cbk   = ws + 6 * SL;               // [H*B*T]
    float* rbrk  = cbk + BB * TT * HH;        // [H*2T]

    const dim3 gemm_grid(DD / 64, MM / 64);   // (8, 64)

    pe_kernel<<<(2 * TT * DD) / 256, 256, 0, stream>>>(pe);
    gemm_bias_kernel<<<gemm_grid, 256, 0, stream>>>(pe, Wr, nullptr, relk, MM, DD, DD);
    gemm_bias_kernel<<<gemm_grid, 256, 0, stream>>>(query,  Wq, bq, qb, MM, DD, DD);
    gemm_bias_kernel<<<gemm_grid, 256, 0, stream>>>(key_in, Wk, bk, kb, MM, DD, DD);
    gemm_bias_kernel<<<gemm_grid, 256, 0, stream>>>(value,  Wv, bv, vb, MM, DD, DD);
    bias_dots_kernel<<<(BB * TT * HH + 2 * TT * HH) / 256, 256, 0, stream>>>(
        kb, relk, cb, rb, cbk, rbrk);
    // prepack order matters (aliasing): V first (frees vb), then K (-> vb),
    // then R (-> kb, after K consumed kb).
    prepack_kernel<<<1024, 256, 0, stream>>>(vb, Vpk, 2);
    prepack_kernel<<<1024, 256, 0, stream>>>(kb, Kpk, 0);
    prepack_kernel<<<1024, 256, 0, stream>>>(relk, Rpk, 1);
    attn_mfma_kernel<<<BB * HH * (TT / 64), 256, 0, stream>>>(
        qb, Kpk, Vpk, Rpk, cbk, rbrk, attnv);
    gemm_bias_kernel<<<gemm_grid, 256, 0, stream>>>(attnv, Wo, bo, out, MM, DD, DD);
}

// Round 7
// 371.932 us; speedup vs baseline: 2.1754x; 1.3079x over previous
//
#include <hip/hip_runtime.h>
#include <math.h>

// Problem constants: B=2, T=2048, H=8, Dk=64, D=512
#define BB 2
#define TT 2048
#define HH 8
#define DK 64
#define DD 512
#define MM (BB * TT)

typedef unsigned int u32;
typedef unsigned short u16;
typedef __bf16 bf16x8 __attribute__((ext_vector_type(8)));
typedef float f32x4 __attribute__((ext_vector_type(4)));

union frag_u { bf16x8 f; u16 u[8]; u32 w[4]; };

// fp32 -> bf16 hi + bf16 lo (RNE both); x ~= hi + lo to ~2^-20 rel.
__device__ __forceinline__ void split2(float x, u16& h, u16& l) {
    u32 u = __float_as_uint(x);
    u32 hi = (u + 0x7fffu + ((u >> 16) & 1u)) >> 16;
    float hif = __uint_as_float(hi << 16);
    float lof = x - hif;                       // exact
    u32 ul = __float_as_uint(lof);
    u32 lo = (ul + 0x7fffu + ((ul >> 16) & 1u)) >> 16;
    h = (u16)hi; l = (u16)lo;
}
__device__ __forceinline__ u32 split_pack(float x) {
    u16 h, l; split2(x, h, l);
    return ((u32)h << 16) | (u32)l;
}

// async global->LDS, 16B per lane, LDS dest = wave-uniform base + lane*16
__device__ __forceinline__ void load_lds16(const void* g, void* l) {
    __builtin_amdgcn_global_load_lds(
        (const __attribute__((address_space(1))) void*)g,
        (__attribute__((address_space(3))) void*)l, 16, 0, 0);
}

// ---------------------------------------------------------------------------
// Sinusoid position encoding (fp64 math to match numpy float64 path).
// ---------------------------------------------------------------------------
__global__ __launch_bounds__(256) void pe_kernel(float* __restrict__ pe) {
    int idx = blockIdx.x * 256 + threadIdx.x;
    int m   = idx >> 9;
    int col = idx & 511;
    int j   = col & 255;
    double inv_freq = exp((double)(-2 * j) * (9.210340371976184 / 512.0));
    double ang = (double)(TT - m) * inv_freq;
    pe[idx] = (col < 256) ? (float)sin(ang) : (float)cos(ang);
}

// ---------------------------------------------------------------------------
// Bias-fold dots, PRESCALED by 1/8, stored HEAD-MAJOR:
//   cbk[(h*B + b)*T + t]  = 0.125 * content_bias[h] . k[b,t,h,:]
//   rbrk[h*2T + m]        = 0.125 * relative_bias[h] . relk[m,h,:]
// ---------------------------------------------------------------------------
__global__ __launch_bounds__(256) void bias_dots_kernel(
    const float* __restrict__ kmat, const float* __restrict__ relk,
    const float* __restrict__ cb, const float* __restrict__ rb,
    float* __restrict__ cbk, float* __restrict__ rbrk) {
    int idx = blockIdx.x * 256 + threadIdx.x;
    if (idx < BB * TT * HH) {
        int h = idx & (HH - 1);
        int bt = idx >> 3;                 // b*T + t
        int b = bt >> 11, t = bt & (TT - 1);
        const float* kp  = kmat + (size_t)idx * DK;
        const float* cbp = cb + h * DK;
        float s = 0.f;
#pragma unroll
        for (int d = 0; d < DK; d++) s += cbp[d] * kp[d];
        cbk[((size_t)h * BB + b) * TT + t] = s * 0.125f;
    } else {
        int i2 = idx - BB * TT * HH;       // m*H + h
        int h = i2 & (HH - 1);
        int m = i2 >> 3;
        const float* rp  = relk + (size_t)i2 * DK;
        const float* rbp = rb + h * DK;
        float s = 0.f;
#pragma unroll
        for (int d = 0; d < DK; d++) s += rbp[d] * rp[d];
        rbrk[(size_t)h * (2 * TT) + m] = s * 0.125f;
    }
}

// ---------------------------------------------------------------------------
// Prepack fp32 32x64 tiles into swizzled hi/lo bf16 granule layout (8 KB/tile,
// hi at [0,4KB), lo at [4,8KB)).
//   mode 0: K tiles   (bid: b=bid>>9, h=(bid>>6)&7, jt=bid&63), B-frag layout
//   mode 1: R chunks  (bid: h=bid>>7, cidx=bid&127),            B-frag layout
//   mode 2: V tiles   (K-style bid), transposed V-frag layout
// K/R granule: g = nt*128 + n*8 + ((4s+kq+5n)&7)  [row n of 16, nt=row>>4,
//              d = s*32+kq*8+e]   -> frag read is phase-conflict-free.
// V granule:   g = ntd*64 + n*4 + ((kq+(n>>1))&3) [col d=ntd*16+n, j=kq*8+e]
// ---------------------------------------------------------------------------
__global__ __launch_bounds__(256) void prepack_kernel(
    const float* __restrict__ src, u16* __restrict__ dst, int mode) {
    __shared__ float tf[32][68];
    const int bid = blockIdx.x, tid = threadIdx.x;
    size_t soff;
    if (mode == 1) soff = ((size_t)(bid & 127) * 256 + (size_t)(bid >> 7)) * 64;
    else soff = ((size_t)(bid >> 9) * 2048 + (size_t)(bid & 63) * 32) * 512
                + (size_t)((bid >> 6) & 7) * 64;
    u16* dt = dst + (size_t)bid * 4096;
    const int r = tid >> 3, f = tid & 7;
    const float* p = src + soff + (size_t)r * 512 + (size_t)f * 8;
    float4 a  = *(const float4*)p;
    float4 b4 = *(const float4*)(p + 4);
    if (mode == 2) {
        *(float4*)&tf[r][f * 8]     = a;
        *(float4*)&tf[r][f * 8 + 4] = b4;
        __syncthreads();
        const int d = tid >> 2, kq = tid & 3;
        u32 hw[4], lw[4];
#pragma unroll
        for (int e = 0; e < 4; e++) {
            u16 h0, l0, h1, l1;
            split2(tf[kq * 8 + 2 * e][d], h0, l0);
            split2(tf[kq * 8 + 2 * e + 1][d], h1, l1);
            hw[e] = (u32)h0 | ((u32)h1 << 16);
            lw[e] = (u32)l0 | ((u32)l1 << 16);
        }
        const int n = d & 15;
        const int g = (d >> 4) * 64 + n * 4 + ((kq + (n >> 1)) & 3);
        *(uint4*)(dt + g * 8)        = make_uint4(hw[0], hw[1], hw[2], hw[3]);
        *(uint4*)(dt + 2048 + g * 8) = make_uint4(lw[0], lw[1], lw[2], lw[3]);
    } else {
        float xs[8] = {a.x, a.y, a.z, a.w, b4.x, b4.y, b4.z, b4.w};
        u32 hw[4], lw[4];
#pragma unroll
        for (int e = 0; e < 4; e++) {
            u16 h0, l0, h1, l1;
            split2(xs[2 * e], h0, l0);
            split2(xs[2 * e + 1], h1, l1);
            hw[e] = (u32)h0 | ((u32)h1 << 16);
            lw[e] = (u32)l0 | ((u32)l1 << 16);
        }
        const int s = f >> 2, kq = f & 3, nt = r >> 4, n = r & 15;
        const int g = nt * 128 + n * 8 + ((4 * s + kq + 5 * n) & 7);
        *(uint4*)(dt + g * 8)        = make_uint4(hw[0], hw[1], hw[2], hw[3]);
        *(uint4*)(dt + 2048 + g * 8) = make_uint4(lw[0], lw[1], lw[2], lw[3]);
    }
}

// ---------------------------------------------------------------------------
// Prepack a GEMM A-operand: fp32 [4096,512] -> 32-row x 64-k hi/lo granule
// tiles (same granule layout/swizzle as mode 0). bid: rb = bid>>3 (row-block
// of 32), kb = bid&7 (k-block of 64). Grid 1024.
// ---------------------------------------------------------------------------
__global__ __launch_bounds__(256) void prepack_a_kernel(
    const float* __restrict__ src, u16* __restrict__ dst) {
    const int bid = blockIdx.x, tid = threadIdx.x;
    const int r = tid >> 3, f = tid & 7;
    const float* p = src + ((size_t)(bid >> 3) * 32 + r) * 512
                         + (size_t)(bid & 7) * 64 + f * 8;
    float4 a  = *(const float4*)p;
    float4 b4 = *(const float4*)(p + 4);
    float xs[8] = {a.x, a.y, a.z, a.w, b4.x, b4.y, b4.z, b4.w};
    u32 hw[4], lw[4];
#pragma unroll
    for (int e = 0; e < 4; e++) {
        u16 h0, l0, h1, l1;
        split2(xs[2 * e], h0, l0);
        split2(xs[2 * e + 1], h1, l1);
        hw[e] = (u32)h0 | ((u32)h1 << 16);
        lw[e] = (u32)l0 | ((u32)l1 << 16);
    }
    const int s = f >> 2, kq = f & 3, nt = r >> 4, n = r & 15;
    const int g = nt * 128 + n * 8 + ((4 * s + kq + 5 * n) & 7);
    u16* dt = dst + (size_t)bid * 4096;
    *(uint4*)(dt + g * 8)        = make_uint4(hw[0], hw[1], hw[2], hw[3]);
    *(uint4*)(dt + 2048 + g * 8) = make_uint4(lw[0], lw[1], lw[2], lw[3]);
}

// ---------------------------------------------------------------------------
// Prepack 5 weight matrices [512,512] into B-frag hi/lo granule tiles of
// 32 cols x 64 k (transposed via LDS). bid: widx = bid>>7 picks the weight,
// loc = bid&127: nb2 = loc>>3 (col-block of 32), kb = loc&7 (k-block of 64).
// Grid 640. Per-weight region = 128 tiles * 4096 u16 = 1 MB.
// ---------------------------------------------------------------------------
__global__ __launch_bounds__(256) void prepack_w_kernel(
    const float* __restrict__ W0, const float* __restrict__ W1,
    const float* __restrict__ W2, const float* __restrict__ W3,
    const float* __restrict__ W4, u16* __restrict__ dst) {
    __shared__ float tw[64][36];
    const int bid = blockIdx.x, tid = threadIdx.x;
    const int widx = bid >> 7, loc = bid & 127;
    const int nb2 = loc >> 3, kb = loc & 7;
    const float* Wsrc = widx == 0 ? W0 : widx == 1 ? W1 : widx == 2 ? W2
                      : widx == 3 ? W3 : W4;
    const int kl = tid >> 2, gr = tid & 3;
    const float* p = Wsrc + (size_t)(kb * 64 + kl) * 512 + nb2 * 32 + gr * 8;
    float4 a  = *(const float4*)p;
    float4 b4 = *(const float4*)(p + 4);
    *(float4*)&tw[kl][gr * 8]     = a;
    *(float4*)&tw[kl][gr * 8 + 4] = b4;
    __syncthreads();
    const int n5 = tid >> 3, f = tid & 7, s = f >> 2, kq = f & 3;
    u32 hw[4], lw[4];
#pragma unroll
    for (int e = 0; e < 4; e++) {
        u16 h0, l0, h1, l1;
        split2(tw[s * 32 + kq * 8 + 2 * e][n5], h0, l0);
        split2(tw[s * 32 + kq * 8 + 2 * e + 1][n5], h1, l1);
        hw[e] = (u32)h0 | ((u32)h1 << 16);
        lw[e] = (u32)l0 | ((u32)l1 << 16);
    }
    const int n = n5 & 15, nt = n5 >> 4;
    const int g = nt * 128 + n * 8 + ((4 * s + kq + 5 * n) & 7);
    u16* dt = dst + (size_t)bid * 4096;
    *(uint4*)(dt + g * 8)        = make_uint4(hw[0], hw[1], hw[2], hw[3]);
    *(uint4*)(dt + 2048 + g * 8) = make_uint4(lw[0], lw[1], lw[2], lw[3]);
}

// ---------------------------------------------------------------------------
// MFMA GEMM, bf16 hi/lo emulation: C[4096,512] = A @ W + bias, fp32 I/O via
// prepacked hi/lo granule tiles. 64x64 tile, BK=64, 4 waves each 32x32.
// C = Ah*Wh + Ah*Wl + Al*Wh  (lo*lo dropped, ~2^-20 rel).
// XCD swizzle: bx = nb*64 + mp -> all 8 n-blocks of one A-panel on one XCD.
// Double-buffered global_load_lds staging (2 x 32 KB), 1 barrier/kstep.
// ---------------------------------------------------------------------------
__global__ __launch_bounds__(256, 2) void gemm_mfma_kernel(
    const u16* __restrict__ Apk, const u16* __restrict__ Wpk,
    const float* __restrict__ bias, float* __restrict__ C) {
    __shared__ __align__(16) u16 Stage[2][16384];   // [half][A0 A1 W0 W1] 8KB ea

    const int tid = threadIdx.x;
    const int w = tid >> 6, lane = tid & 63, quad = lane >> 4, c = lane & 15;
    const int bx = blockIdx.x;
    const int mp = bx & 63, nb = bx >> 6;
    const int mq = w >> 1, nq = w & 1;

    auto stage_async = [&](int kb, int half) {
        const u16* s = (w < 2)
            ? Apk + (size_t)((2 * mp + w) * 8 + kb) * 4096
            : Wpk + (size_t)((2 * nb + (w & 1)) * 8 + kb) * 4096;
        const u16* g = s + lane * 8;
        u16* d = Stage[half] + w * 4096;
#pragma unroll
        for (int u2 = 0; u2 < 8; u2++)
            load_lds16(g + u2 * 512, d + u2 * 512);
    };

    stage_async(0, 0);

    f32x4 acc[2][2];
#pragma unroll
    for (int mh = 0; mh < 2; mh++)
#pragma unroll
        for (int nh = 0; nh < 2; nh++) acc[mh][nh] = (f32x4){0.f, 0.f, 0.f, 0.f};

    for (int kb = 0; kb < 8; kb++) {
        const int half = kb & 1;
        __syncthreads();          // drains this half's DMA; prior reads done
        if (kb < 7) stage_async(kb + 1, 1 - half);
        const u16* Ab = Stage[half] + mq * 4096;
        const u16* Wb = Stage[half] + 8192 + nq * 4096;
#pragma unroll
        for (int s = 0; s < 2; s++) {
            bf16x8 ah[2], al[2], wh[2], wl[2];
#pragma unroll
            for (int t = 0; t < 2; t++) {
                int g = (t << 7) + (c << 3) + (((s << 2) + quad + 5 * c) & 7);
                ah[t] = *(const bf16x8*)(Ab + g * 8);
                al[t] = *(const bf16x8*)(Ab + 2048 + g * 8);
                wh[t] = *(const bf16x8*)(Wb + g * 8);
                wl[t] = *(const bf16x8*)(Wb + 2048 + g * 8);
            }
#pragma unroll
            for (int mh = 0; mh < 2; mh++)
#pragma unroll
                for (int nh = 0; nh < 2; nh++) {
                    acc[mh][nh] = __builtin_amdgcn_mfma_f32_16x16x32_bf16(
                        ah[mh], wh[nh], acc[mh][nh], 0, 0, 0);
                    acc[mh][nh] = __builtin_amdgcn_mfma_f32_16x16x32_bf16(
                        ah[mh], wl[nh], acc[mh][nh], 0, 0, 0);
                    acc[mh][nh] = __builtin_amdgcn_mfma_f32_16x16x32_bf16(
                        al[mh], wh[nh], acc[mh][nh], 0, 0, 0);
                }
        }
    }

    // epilogue: C row = m0 + mh*16 + quad*4 + r, col = n0 + nh*16 + c
    const int m0 = mp * 64 + mq * 32, n0 = nb * 64 + nq * 32;
    float bv0 = bias ? bias[n0 + c] : 0.f;
    float bv1 = bias ? bias[n0 + 16 + c] : 0.f;
#pragma unroll
    for (int mh = 0; mh < 2; mh++)
#pragma unroll
        for (int r = 0; r < 4; r++) {
            size_t row = (size_t)(m0 + mh * 16 + quad * 4 + r) * 512;
            C[row + n0 + c]      = acc[mh][0][r] + bv0;
            C[row + n0 + 16 + c] = acc[mh][1][r] + bv1;
        }
}

// ---------------------------------------------------------------------------
// MFMA flash attention with Transformer-XL rel-shift (unchanged from R5/R6).
// ---------------------------------------------------------------------------
__global__ __launch_bounds__(256, 2) void attn_mfma_kernel(
    const float* __restrict__ q, const u16* __restrict__ Kpk,
    const u16* __restrict__ Vpk, const u16* __restrict__ Rpk,
    const float* __restrict__ cbk, const float* __restrict__ rbrk,
    float* __restrict__ attn_out) {
    __shared__ __align__(16) u16 Stage[2][8192];   // [half][ K(4096) | V(4096) ]
    __shared__ float Ring[4 * 4 * 560];            // [wave][slot][16][35]
    __shared__ u32 Pbuf[4 * 544];                  // [wave][16][34]

    const int tid = threadIdx.x;
    const int w = tid >> 6, lane = tid & 63, quad = lane >> 4, c = lane & 15;
    const int bx = blockIdx.x;
    const int h = bx & 7, b = (bx >> 3) & 1, it0 = bx >> 4;   // h in low bits
    const int i0 = it0 * 64;
    const size_t bh_off = (size_t)b * TT * DD + (size_t)h * DK;

    frag_u qh[2], ql[2];
    {
        const float* qrow = q + bh_off + (size_t)(i0 + 16 * w + c) * DD;
#pragma unroll
        for (int s = 0; s < 2; s++) {
            int d0 = s * 32 + quad * 8;
            float4 a  = *(const float4*)(qrow + d0);
            float4 b4 = *(const float4*)(qrow + d0 + 4);
            float xs[8] = {a.x, a.y, a.z, a.w, b4.x, b4.y, b4.z, b4.w};
#pragma unroll
            for (int j2 = 0; j2 < 8; j2++)
                split2(xs[j2] * 0.125f, qh[s].u[j2], ql[s].u[j2]);
        }
    }

    const u16* Ktiles  = Kpk + (size_t)(b * HH + h) * 64 * 4096;
    const u16* Vtiles  = Vpk + (size_t)(b * HH + h) * 64 * 4096;
    const u16* Rchunks = Rpk + (size_t)h * 128 * 4096;
    const float* rbrk_h = rbrk + (size_t)h * (2 * TT);
    const float* cbk_h  = cbk + ((size_t)h * BB + b) * TT;

    auto read_kr = [&](const u16* reg, int nt, int s, bf16x8& fh, bf16x8& fl) {
        int g = (nt << 7) + (c << 3) + (((s << 2) + quad + 5 * c) & 7);
        fh = *(const bf16x8*)(reg + g * 8);
        fl = *(const bf16x8*)(reg + 2048 + g * 8);
    };
    auto read_v = [&](const u16* Vb, int ntd, bf16x8& fh, bf16x8& fl) {
        int g = ntd * 64 + c * 4 + ((quad + (c >> 1)) & 3);
        fh = *(const bf16x8*)(Vb + g * 8);
        fl = *(const bf16x8*)(Vb + 2048 + g * 8);
    };

    const int k0c = (TT - i0 - 63) >> 5;

    auto produce = [&](int cidx) {
        const u16* Rc = Rchunks + (size_t)cidx * 4096;
        float* ringw = Ring + (w * 4 + (cidx & 3)) * 560;
#pragma unroll
        for (int ntp = 0; ntp < 2; ntp++) {
            f32x4 acc = {0.f, 0.f, 0.f, 0.f};
#pragma unroll
            for (int s = 0; s < 2; s++) {
                int g = (ntp << 7) + (c << 3) + (((s << 2) + quad + 5 * c) & 7);
                bf16x8 fh = *(const bf16x8*)(Rc + g * 8);
                bf16x8 fl = *(const bf16x8*)(Rc + 2048 + g * 8);
                acc = __builtin_amdgcn_mfma_f32_16x16x32_bf16(qh[s].f, fh, acc, 0, 0, 0);
                acc = __builtin_amdgcn_mfma_f32_16x16x32_bf16(qh[s].f, fl, acc, 0, 0, 0);
                acc = __builtin_amdgcn_mfma_f32_16x16x32_bf16(ql[s].f, fh, acc, 0, 0, 0);
            }
            float rbv = rbrk_h[cidx * 32 + ntp * 16 + c];
            int mpos = ntp * 16 + c;
#pragma unroll
            for (int r = 0; r < 4; r++)
                ringw[(quad * 4 + r) * 35 + mpos] = acc[r] + rbv;
        }
    };

    auto stage_async = [&](int jn, int half) {
        const u16* Ks = Ktiles + (size_t)jn * 4096;
        const u16* Vs = Vtiles + (size_t)jn * 4096;
        u16* dst = Stage[half];
#pragma unroll
        for (int u = 0; u < 4; u++) {
            int ch = w * 4 + u;
            int rg = ch >> 3;
            int of = (ch & 7) << 9;
            const u16* g = (rg ? Vs : Ks) + of + lane * 8;
            load_lds16(g, dst + (rg << 12) + of);
        }
    };

    stage_async(0, 0);
    produce(k0c);
    produce(k0c + 1);

    float m_run[4], l_run[4];
    f32x4 o[4];
#pragma unroll
    for (int r = 0; r < 4; r++) { m_run[r] = -INFINITY; l_run[r] = 0.f; }
#pragma unroll
    for (int nt = 0; nt < 4; nt++) o[nt] = (f32x4){0.f, 0.f, 0.f, 0.f};

    for (int jt = 0; jt < TT / 32; jt++) {
        const int j0 = jt * 32;
        const int half = jt & 1;
        const u16* Kb = Stage[half];
        const u16* Vb = Stage[half] + 4096;
        __syncthreads();
        if (jt < TT / 32 - 1) stage_async(jt + 1, 1 - half);

        produce(k0c + jt + 2);

        const int mb0 = TT - i0 - 16 * w + j0;
        float cbv0 = cbk_h[j0 + c];
        float cbv1 = cbk_h[j0 + 16 + c];
        float sv[2][4];
#pragma unroll
        for (int nt = 0; nt < 2; nt++) {
            f32x4 sc = {0.f, 0.f, 0.f, 0.f};
#pragma unroll
            for (int s = 0; s < 2; s++) {
                bf16x8 fh, fl;
                read_kr(Kb, nt, s, fh, fl);
                sc = __builtin_amdgcn_mfma_f32_16x16x32_bf16(qh[s].f, fh, sc, 0, 0, 0);
                sc = __builtin_amdgcn_mfma_f32_16x16x32_bf16(qh[s].f, fl, sc, 0, 0, 0);
                sc = __builtin_amdgcn_mfma_f32_16x16x32_bf16(ql[s].f, fh, sc, 0, 0, 0);
            }
            int mc = mb0 + nt * 16 + c;
            float cbv = nt ? cbv1 : cbv0;
#pragma unroll
            for (int r = 0; r < 4; r++) {
                int row16 = quad * 4 + r;
                int m_abs = mc - row16;
                float rel = Ring[(w * 4 + ((m_abs >> 5) & 3)) * 560
                                 + row16 * 35 + (m_abs & 31)];
                sv[nt][r] = sc[r] + rel + cbv;
            }
        }

#pragma unroll
        for (int r = 0; r < 4; r++) {
            float tm = fmaxf(sv[0][r], sv[1][r]);
#pragma unroll
            for (int off = 1; off < 16; off <<= 1) tm = fmaxf(tm, __shfl_xor(tm, off));
            float mnew = fmaxf(m_run[r], tm);
            float al = __expf(m_run[r] - mnew);
            float p0 = __expf(sv[0][r] - mnew);
            float p1 = __expf(sv[1][r] - mnew);
            float ps = p0 + p1;
#pragma unroll
            for (int off = 1; off < 16; off <<= 1) ps += __shfl_xor(ps, off);
            l_run[r] = l_run[r] * al + ps;
            m_run[r] = mnew;
#pragma unroll
            for (int nt = 0; nt < 4; nt++) o[nt][r] *= al;
            u32* pb = Pbuf + w * 544 + (quad * 4 + r) * 34;
            pb[c]      = split_pack(p0);
            pb[16 + c] = split_pack(p1);
        }

        frag_u ph, pl;
        {
            const u32* pb = Pbuf + w * 544 + c * 34 + quad * 8;
            uint2 r0 = *(const uint2*)(pb);
            uint2 r1 = *(const uint2*)(pb + 2);
            uint2 r2 = *(const uint2*)(pb + 4);
            uint2 r3 = *(const uint2*)(pb + 6);
            u32 pk[8] = {r0.x, r0.y, r1.x, r1.y, r2.x, r2.y, r3.x, r3.y};
#pragma unroll
            for (int j2 = 0; j2 < 8; j2++) {
                ph.u[j2] = (u16)(pk[j2] >> 16);
                pl.u[j2] = (u16)(pk[j2] & 0xffffu);
            }
        }
#pragma unroll
        for (int ntd = 0; ntd < 4; ntd++) {
            bf16x8 vh, vl;
            read_v(Vb, ntd, vh, vl);
            o[ntd] = __builtin_amdgcn_mfma_f32_16x16x32_bf16(ph.f, vh, o[ntd], 0, 0, 0);
            o[ntd] = __builtin_amdgcn_mfma_f32_16x16x32_bf16(ph.f, vl, o[ntd], 0, 0, 0);
            o[ntd] = __builtin_amdgcn_mfma_f32_16x16x32_bf16(pl.f, vh, o[ntd], 0, 0, 0);
        }
    }

#pragma unroll
    for (int nt = 0; nt < 4; nt++) {
#pragma unroll
        for (int r = 0; r < 4; r++) {
            int row16 = quad * 4 + r;
            int i_abs = i0 + 16 * w + row16;
            attn_out[((size_t)b * TT + i_abs) * DD + h * DK + nt * 16 + c] =
                o[nt][r] / l_run[r];
        }
    }
}

// ---------------------------------------------------------------------------
extern "C" void kernel_launch(void* const* d_in, const int* in_sizes, int n_in,
                              void* d_out, int out_size, void* d_ws, size_t ws_size,
                              hipStream_t stream) {
    const float* query  = (const float*)d_in[0];
    const float* key_in = (const float*)d_in[1];
    const float* value  = (const float*)d_in[2];
    const float* Wq = (const float*)d_in[3];
    const float* bq = (const float*)d_in[4];
    const float* Wk = (const float*)d_in[5];
    const float* bk = (const float*)d_in[6];
    const float* Wv = (const float*)d_in[7];
    const float* bv = (const float*)d_in[8];
    const float* Wr = (const float*)d_in[9];
    const float* cb = (const float*)d_in[10];
    const float* rb = (const float*)d_in[11];
    const float* Wo = (const float*)d_in[12];
    const float* bo = (const float*)d_in[13];
    float* out = (float*)d_out;

    float* ws = (float*)d_ws;
    const size_t SL = (size_t)MM * DD;        // 2097152 floats (8 MB) per slot
    float* qb    = ws;                        // fp32 Q [B,T,H,Dk]
    float* kb    = ws + SL;                   // fp32 K (consumed, then holds Rpk)
    float* vb    = ws + 2 * SL;               // fp32 V (consumed, then holds Kpk)
    float* relk  = ws + 3 * SL;               // fp32 relK [2T,H,Dk]
    float* attnv = ws + 4 * SL;               // attn output (pe aliased here first)
    float* pe    = attnv;                     // pe consumed before attnv written
    u16*   Vpk   = (u16*)(ws + 5 * SL);       // packed V tiles (8 MB)
    u16*   Kpk   = (u16*)vb;                  // packed K tiles (8 MB)
    u16*   Rpk   = (u16*)kb;                  // packed R chunks (8 MB)
    u16*   Apk   = (u16*)(ws + 6 * SL);       // packed GEMM A operand (8 MB, reused)
    u16*   Wpk   = (u16*)(ws + 7 * SL);       // packed weights, 5 x 1 MB
    float* cbk   = ws + 7 * SL + 1310720;     // [H*B*T]
    float* rbrk  = cbk + BB * TT * HH;        // [H*2T]
    const size_t WSZ = 128 * 4096;            // u16 per packed weight

    // weights + pe
    prepack_w_kernel<<<640, 256, 0, stream>>>(Wq, Wk, Wv, Wr, Wo, Wpk);
    pe_kernel<<<(2 * TT * DD) / 256, 256, 0, stream>>>(pe);

    // rel_k = pe @ Wr (no bias)
    prepack_a_kernel<<<1024, 256, 0, stream>>>(pe, Apk);
    gemm_mfma_kernel<<<512, 256, 0, stream>>>(Apk, Wpk + 3 * WSZ, nullptr, relk);
    // projections (Apk reused serially)
    prepack_a_kernel<<<1024, 256, 0, stream>>>(query, Apk);
    gemm_mfma_kernel<<<512, 256, 0, stream>>>(Apk, Wpk + 0 * WSZ, bq, qb);
    prepack_a_kernel<<<1024, 256, 0, stream>>>(key_in, Apk);
    gemm_mfma_kernel<<<512, 256, 0, stream>>>(Apk, Wpk + 1 * WSZ, bk, kb);
    prepack_a_kernel<<<1024, 256, 0, stream>>>(value, Apk);
    gemm_mfma_kernel<<<512, 256, 0, stream>>>(Apk, Wpk + 2 * WSZ, bv, vb);

    bias_dots_kernel<<<(BB * TT * HH + 2 * TT * HH) / 256, 256, 0, stream>>>(
        kb, relk, cb, rb, cbk, rbrk);
    // prepack order matters (aliasing): V first (frees vb), then K (-> vb),
    // then R (-> kb, after K consumed kb).
    prepack_kernel<<<1024, 256, 0, stream>>>(vb, Vpk, 2);
    prepack_kernel<<<1024, 256, 0, stream>>>(kb, Kpk, 0);
    prepack_kernel<<<1024, 256, 0, stream>>>(relk, Rpk, 1);
    attn_mfma_kernel<<<BB * HH * (TT / 64), 256, 0, stream>>>(
        qb, Kpk, Vpk, Rpk, cbk, rbrk, attnv);
    // output projection
    prepack_a_kernel<<<1024, 256, 0, stream>>>(attnv, Apk);
    gemm_mfma_kernel<<<512, 256, 0, stream>>>(Apk, Wpk + 4 * WSZ, bo, out);
}